// Round 11
// baseline (393.634 us; speedup 1.0000x reference)
//
#include <hip/hip_runtime.h>

// Neurcomp / SIREN MLP inference — round 17: r16 + permuted feature->tile
// assignment; h-transpose LDS round-trip eliminated.
// r16 post-mortem: 4-chain split worked (315->305, MfmaUtil 41.7, issue 88%).
// Remaining ~12% stall = the two per-layer LDS transpose turnarounds.
// Fix: output feature of tile t, row m is now feat = 32(t&3)+8(m>>2)+4(t>>2)
// +(m&3) (bijection). Then mm2/F0 D-registers ARE the next mm1 B-fragment
// order: FH[kc] = PK8(H[kc], H[kc+4]) — in-register, no LDS. W1 outputs get
// the same permutation, so s1 staging reads become blocks (4kc+q)^lnk and
// (4kc+16+q)^lnk. K-mappings of both A-preps untouched -> every feature's
// dot product / bias / sin is BIT-IDENTICAL to r16 (absmax must be exactly
// 4.8828e-4). DS ops/layer 64->32. Bias/w0/wf loads stay contiguous f4v at
// offset 32(t&3)+4(t>>2)+8q.
// Layouts (learn_hip m89/m120, r6/r8-verified): A[m=lane&15][k=(lane>>4)*8+j],
// B[k=(lane>>4)*8+j][n=lane&15], D row=(lane>>4)*4+reg, col=lane&15.
// A = weights, B = activations; D: feature row, point col.

typedef unsigned int u32;
typedef short s8v __attribute__((ext_vector_type(8)));   // 8 bf16 (bits)
typedef float f4v __attribute__((ext_vector_type(4)));
typedef u32   u4v __attribute__((ext_vector_type(4)));

constexpr float OMEGA = 30.0f;
constexpr int HID = 128, NRES = 7, BT = 256;
constexpr int WROW = 136;              // dwords per LDS row: 32 b128-blocks + pad
constexpr int WAVE_LDS = 32 * WROW;    // 4352 dwords per wave (32 rows)
constexpr int FRAG_ELEMS = 14 * 16384; // bf16 elems per hi/lo ws array

__device__ __forceinline__ float sin_om(float z) {
    float r = z * (OMEGA * 0.15915494309189535f);
    r = r - floorf(r);
    return __builtin_amdgcn_sinf(r);
}
__device__ __forceinline__ f4v mfma16(s8v a, s8v b, f4v c) {
    return __builtin_amdgcn_mfma_f32_16x16x32_bf16(a, b, c, 0, 0, 0);
}
__device__ __forceinline__ u32 fu(float f) { return __builtin_bit_cast(u32, f); }
__device__ __forceinline__ float andf(float f) {
    return __builtin_bit_cast(float, __builtin_bit_cast(u32, f) & 0xffff0000u);
}
__device__ __forceinline__ s8v bc(u4v v) { return __builtin_bit_cast(s8v, v); }

// 8 fp32 (frag elem order j=0..7) -> hi s8v + lo s8v (truncation split).
// v_perm sel 0x07060302: D = {a.hi16 (top), b.hi16 (low)}.
#define PK8(e0,e1,e2,e3,e4,e5,e6,e7, FH_, FL_) { \
    u4v h_, l_; \
    h_.x = __builtin_amdgcn_perm(fu(e1), fu(e0), 0x07060302u); \
    h_.y = __builtin_amdgcn_perm(fu(e3), fu(e2), 0x07060302u); \
    h_.z = __builtin_amdgcn_perm(fu(e5), fu(e4), 0x07060302u); \
    h_.w = __builtin_amdgcn_perm(fu(e7), fu(e6), 0x07060302u); \
    float L0_ = e0 - andf(e0), L1_ = e1 - andf(e1); \
    float L2_ = e2 - andf(e2), L3_ = e3 - andf(e3); \
    float L4_ = e4 - andf(e4), L5_ = e5 - andf(e5); \
    float L6_ = e6 - andf(e6), L7_ = e7 - andf(e7); \
    l_.x = __builtin_amdgcn_perm(fu(L1_), fu(L0_), 0x07060302u); \
    l_.y = __builtin_amdgcn_perm(fu(L3_), fu(L2_), 0x07060302u); \
    l_.z = __builtin_amdgcn_perm(fu(L5_), fu(L4_), 0x07060302u); \
    l_.w = __builtin_amdgcn_perm(fu(L7_), fu(L6_), 0x07060302u); \
    FH_ = __builtin_bit_cast(s8v, h_); FL_ = __builtin_bit_cast(s8v, l_); }

// h B-fragments directly from H registers (state is already in B-frag order):
// FH{mt}{kc} elems j=0..3 from H[nt=kc], j=4..7 from H[nt=kc+4].
#define HFRAG(mt, na, nb, FH_, FL_) \
    PK8(H_##mt##_##na##_0, H_##mt##_##na##_1, H_##mt##_##na##_2, H_##mt##_##na##_3, \
        H_##mt##_##nb##_0, H_##mt##_##nb##_1, H_##mt##_##nb##_2, H_##mt##_##nb##_3, \
        FH_, FL_)

// s1 from LDS -> B-fragments (permuted blocks): j=0..3 at block (4kc+q)^lnk
// (written by t=kc), j=4..7 at block (4kc+16+q)^lnk (written by t=kc+4).
#define RT(mt,kc) { \
    const int rb_ = mt ? rowbase1 : rowbase0; \
    f4v u_ = *(const f4v*)&buf[rb_ + ((((kc)*4 + q) ^ lnk) << 2)]; \
    f4v v_ = *(const f4v*)&buf[rb_ + ((((kc)*4 + 16 + q) ^ lnk) << 2)]; \
    PK8(u_.x, u_.y, u_.z, u_.w, v_.x, v_.y, v_.z, v_.w, FH##mt##kc, FL##mt##kc) }

// prefetch weight tile + bias into buffer S (S = a or b)
#define PF(S, fbv, bp) { \
    g##S##0 = whi[fbv]; g##S##1 = whi[(fbv)+64]; \
    g##S##2 = whi[(fbv)+128]; g##S##3 = whi[(fbv)+192]; \
    r##S##0 = wlo[fbv]; r##S##1 = wlo[(fbv)+64]; \
    r##S##2 = wlo[(fbv)+128]; r##S##3 = wlo[(fbv)+192]; \
    cv##S = *(const f4v*)(bp); }

// 24 MFMAs consuming buffer S — FOUR independent chains, round-robin (r16).
#define MMB4(S) { \
    s8v h0_=bc(g##S##0), l0_=bc(r##S##0), h1_=bc(g##S##1), l1_=bc(r##S##1); \
    s8v h2_=bc(g##S##2), l2_=bc(r##S##2), h3_=bc(g##S##3), l3_=bc(r##S##3); \
    c0  = mfma16(h0_, FH00, c0 ); c1  = mfma16(h0_, FH10, c1 ); \
    c0b = mfma16(h2_, FH02, c0b); c1b = mfma16(h2_, FH12, c1b); \
    c0  = mfma16(h0_, FL00, c0 ); c1  = mfma16(h0_, FL10, c1 ); \
    c0b = mfma16(h2_, FL02, c0b); c1b = mfma16(h2_, FL12, c1b); \
    c0  = mfma16(l0_, FH00, c0 ); c1  = mfma16(l0_, FH10, c1 ); \
    c0b = mfma16(l2_, FH02, c0b); c1b = mfma16(l2_, FH12, c1b); \
    c0  = mfma16(h1_, FH01, c0 ); c1  = mfma16(h1_, FH11, c1 ); \
    c0b = mfma16(h3_, FH03, c0b); c1b = mfma16(h3_, FH13, c1b); \
    c0  = mfma16(h1_, FL01, c0 ); c1  = mfma16(h1_, FL11, c1 ); \
    c0b = mfma16(h3_, FL03, c0b); c1b = mfma16(h3_, FL13, c1b); \
    c0  = mfma16(l1_, FH01, c0 ); c1  = mfma16(l1_, FH11, c1 ); \
    c0b = mfma16(l3_, FH03, c0b); c1b = mfma16(l3_, FH13, c1b); \
    c0 += c0b; c1 += c1b; }

// mm1 step t consuming buffer S: s1 = sin(...), staged to LDS (b128, swizzled)
#define S1(t, S) { \
    f4v c0 = cv##S; f4v c1 = c0; \
    f4v c0b = {0.f, 0.f, 0.f, 0.f}; f4v c1b = c0b; \
    MMB4(S) \
    f4v s0v, s1v; \
    s0v.x = sin_om(c0.x); s0v.y = sin_om(c0.y); \
    s0v.z = sin_om(c0.z); s0v.w = sin_om(c0.w); \
    s1v.x = sin_om(c1.x); s1v.y = sin_om(c1.y); \
    s1v.z = sin_om(c1.z); s1v.w = sin_om(c1.w); \
    const int bo_ = (((t)*4 + q) ^ lnk) << 2; \
    *(f4v*)&buf[rowbase0 + bo_] = s0v; \
    *(f4v*)&buf[rowbase1 + bo_] = s1v; }

// mm2 step t consuming buffer S: epilogue h += s2 (last-layer 0.5 in head)
#define S2(t, S) { \
    f4v c0 = cv##S; f4v c1 = c0; \
    f4v c0b = {0.f, 0.f, 0.f, 0.f}; f4v c1b = c0b; \
    MMB4(S) \
    H_0_##t##_0 += sin_om(c0.x); H_0_##t##_1 += sin_om(c0.y); \
    H_0_##t##_2 += sin_om(c0.z); H_0_##t##_3 += sin_om(c0.w); \
    H_1_##t##_0 += sin_om(c1.x); H_1_##t##_1 += sin_om(c1.y); \
    H_1_##t##_2 += sin_om(c1.z); H_1_##t##_3 += sin_om(c1.w); }

// ---- repetition lists ----
#define LNT8(M) M(0) M(1) M(2) M(3) M(4) M(5) M(6) M(7)
#define LH64(M) \
  M(0,0,0) M(0,0,1) M(0,0,2) M(0,0,3) M(0,1,0) M(0,1,1) M(0,1,2) M(0,1,3) \
  M(0,2,0) M(0,2,1) M(0,2,2) M(0,2,3) M(0,3,0) M(0,3,1) M(0,3,2) M(0,3,3) \
  M(0,4,0) M(0,4,1) M(0,4,2) M(0,4,3) M(0,5,0) M(0,5,1) M(0,5,2) M(0,5,3) \
  M(0,6,0) M(0,6,1) M(0,6,2) M(0,6,3) M(0,7,0) M(0,7,1) M(0,7,2) M(0,7,3) \
  M(1,0,0) M(1,0,1) M(1,0,2) M(1,0,3) M(1,1,0) M(1,1,1) M(1,1,2) M(1,1,3) \
  M(1,2,0) M(1,2,1) M(1,2,2) M(1,2,3) M(1,3,0) M(1,3,1) M(1,3,2) M(1,3,3) \
  M(1,4,0) M(1,4,1) M(1,4,2) M(1,4,3) M(1,5,0) M(1,5,1) M(1,5,2) M(1,5,3) \
  M(1,6,0) M(1,6,1) M(1,6,2) M(1,6,3) M(1,7,0) M(1,7,1) M(1,7,2) M(1,7,3)

#define DH(mt,nt,reg) float H_##mt##_##nt##_##reg;

// first layer: H_{mt}_{nt}_{reg} = feature 32(nt&3)+8q+4(nt>>2)+reg at point.
#define F0(nt) { \
    const int f0_ = 32*((nt)&3) + 4*((nt)>>2) + q8; \
    f4v wa_ = *(const f4v*)(w0p + 3*f0_); \
    f4v wb_ = *(const f4v*)(w0p + 3*f0_ + 4); \
    f4v wc_ = *(const f4v*)(w0p + 3*f0_ + 8); \
    f4v bb_ = *(const f4v*)(b0p + f0_); \
    H_0_##nt##_0 = sin_om(fmaf(wa_.x, X0, fmaf(wa_.y, Y0, fmaf(wa_.z, Z0, bb_.x)))); \
    H_0_##nt##_1 = sin_om(fmaf(wa_.w, X0, fmaf(wb_.x, Y0, fmaf(wb_.y, Z0, bb_.y)))); \
    H_0_##nt##_2 = sin_om(fmaf(wb_.z, X0, fmaf(wb_.w, Y0, fmaf(wc_.x, Z0, bb_.z)))); \
    H_0_##nt##_3 = sin_om(fmaf(wc_.y, X0, fmaf(wc_.z, Y0, fmaf(wc_.w, Z0, bb_.w)))); \
    H_1_##nt##_0 = sin_om(fmaf(wa_.x, X1, fmaf(wa_.y, Y1, fmaf(wa_.z, Z1, bb_.x)))); \
    H_1_##nt##_1 = sin_om(fmaf(wa_.w, X1, fmaf(wb_.x, Y1, fmaf(wb_.y, Z1, bb_.y)))); \
    H_1_##nt##_2 = sin_om(fmaf(wb_.z, X1, fmaf(wb_.w, Y1, fmaf(wc_.x, Z1, bb_.z)))); \
    H_1_##nt##_3 = sin_om(fmaf(wc_.y, X1, fmaf(wc_.z, Y1, fmaf(wc_.w, Z1, bb_.w)))); }

// final head partials (permuted wf index, still contiguous f4v)
#define HF(nt) { \
    const int f0_ = 32*((nt)&3) + 4*((nt)>>2) + q8; \
    f4v wf_ = *(const f4v*)(wfp + f0_); \
    P0 = fmaf(wf_.x, H_0_##nt##_0, fmaf(wf_.y, H_0_##nt##_1, \
         fmaf(wf_.z, H_0_##nt##_2, fmaf(wf_.w, H_0_##nt##_3, P0)))); \
    P1 = fmaf(wf_.x, H_1_##nt##_0, fmaf(wf_.y, H_1_##nt##_1, \
         fmaf(wf_.z, H_1_##nt##_2, fmaf(wf_.w, H_1_##nt##_3, P1)))); }

// ---- weight prep: fp32 W -> hi/lo bf16 fragments, PERMUTED output feature:
// tile t, row m computes feature 32(t&3) + 8(m>>2) + 4(t>>2) + (m&3).
// k-dimension mapping unchanged.
__global__ void prep_kernel(const float* __restrict__ rw1,
                            const float* __restrict__ rw2,
                            unsigned short* __restrict__ wsHi,
                            unsigned short* __restrict__ wsLo) {
    int id = blockIdx.x * 256 + threadIdx.x;      // 0 .. 28671
    int lane = id & 63, kc = (id >> 6) & 3, t = (id >> 8) & 7, L = id >> 11;
    int i = L >> 1;
    bool isW1 = ((L & 1) == 0);
    const float* W = (isW1 ? rw1 : rw2) + i * HID * HID;
    float sc = (isW1 && i > 0) ? 0.5f : 1.0f;     // fold wgt1 (ave_first)
    int m = lane & 15;
    int n = 32 * (t & 3) + 8 * (m >> 2) + 4 * (t >> 2) + (m & 3);  // permuted
    int k0 = kc * 32 + (lane >> 4) * 8;            // input feature base (unchanged)
    const float* src = W + n * HID + k0;           // W[n][k0..k0+7]
    int off = id * 8;
    for (int j = 0; j < 8; ++j) {
        float w = src[j] * sc;
        u32 b = __builtin_bit_cast(u32, w);
        u32 hb = b & 0xffff0000u;
        float lo = w - __builtin_bit_cast(float, hb);
        wsHi[off + j] = (unsigned short)(b >> 16);
        wsLo[off + j] = (unsigned short)(__builtin_bit_cast(u32, lo) >> 16);
    }
}

__global__ void __launch_bounds__(BT)
__attribute__((amdgpu_waves_per_eu(2, 2)))
siren_mfma(const float* __restrict__ x,
           const float* __restrict__ w0p, const float* __restrict__ b0p,
           const float* __restrict__ b1p, const float* __restrict__ b2p,
           const float* __restrict__ wfp, const float* __restrict__ bfp,
           const u4v* __restrict__ whi, const u4v* __restrict__ wlo,
           float* __restrict__ out, int NP)
{
    __shared__ float buf[4 * WAVE_LDS];            // 69632 B, s1 staging only

    const int tid = threadIdx.x;
    const int wv = tid >> 6, lane = tid & 63;
    const int ln = lane & 15, q = lane >> 4;
    const int q8 = q * 8;
    const int lnk = ln & 7;                        // LDS XOR-swizzle key (per row)
    const int rowbase0 = wv * WAVE_LDS + ln * WROW;        // mt0 row (point = ln)
    const int rowbase1 = rowbase0 + 16 * WROW;             // mt1 row (point = 16+ln)
    const int base_pt = blockIdx.x * 128 + wv * 32;

    // ---- first SineLayer, H directly in B-frag-order state
    LH64(DH)
    {
        int p0_ = base_pt + ln;      int i0_ = p0_ < NP ? p0_ : NP - 1;
        int p1_ = base_pt + 16 + ln; int i1_ = p1_ < NP ? p1_ : NP - 1;
        float X0 = x[3*i0_], Y0 = x[3*i0_+1], Z0 = x[3*i0_+2];
        float X1 = x[3*i1_], Y1 = x[3*i1_+1], Z1 = x[3*i1_+2];
        LNT8(F0)
    }

    // activation B-fragments (hi/lo) for 2 point-tiles x 4 k-chunks
    s8v FH00, FH01, FH02, FH03, FH10, FH11, FH12, FH13;
    s8v FL00, FL01, FL02, FL03, FL10, FL11, FL12, FL13;

    // ping-pong prefetch buffers
    u4v ga0, ga1, ga2, ga3, ra0, ra1, ra2, ra3;
    u4v gb0, gb1, gb2, gb3, rb0, rb1, rb2, rb3;
    f4v cva, cvb;

    for (int i = 0; i < NRES; ++i) {
        const int fb1 = (2*i) * 2048 + lane, fb2 = (2*i+1) * 2048 + lane;
        const float* __restrict__ B1l = b1p + i * HID;
        const float* __restrict__ B2l = b2p + i * HID;

        // prefetch mm1-t0; covered by the in-register h fragment build
        PF(a, fb1, B1l + q8)

        // h B-fragments straight from H registers (no LDS)
        HFRAG(0, 0, 4, FH00, FL00) HFRAG(0, 1, 5, FH01, FL01)
        HFRAG(0, 2, 6, FH02, FL02) HFRAG(0, 3, 7, FH03, FL03)
        HFRAG(1, 0, 4, FH10, FL10) HFRAG(1, 1, 5, FH11, FL11)
        HFRAG(1, 2, 6, FH12, FL12) HFRAG(1, 3, 7, FH13, FL13)

        // ---- matmul1 -> s1, software-pipelined (bias offsets permuted)
        PF(b, fb1 + 256,  B1l + 32 + q8)   S1(0, a)
        PF(a, fb1 + 512,  B1l + 64 + q8)   S1(1, b)
        PF(b, fb1 + 768,  B1l + 96 + q8)   S1(2, a)
        PF(a, fb1 + 1024, B1l + 4 + q8)    S1(3, b)
        PF(b, fb1 + 1280, B1l + 36 + q8)   S1(4, a)
        PF(a, fb1 + 1536, B1l + 68 + q8)   S1(5, b)
        PF(b, fb1 + 1792, B1l + 100 + q8)  S1(6, a)
        PF(a, fb2,        B2l + q8)        S1(7, b)   // prefetch mm2-t0

        // s1 -> fragments (split-on-read, permuted blocks)
        RT(0,0) RT(0,1) RT(0,2) RT(0,3)
        RT(1,0) RT(1,1) RT(1,2) RT(1,3)

        // ---- matmul2 -> s2; epilogue h += s2
        PF(b, fb2 + 256,  B2l + 32 + q8)   S2(0, a)
        PF(a, fb2 + 512,  B2l + 64 + q8)   S2(1, b)
        PF(b, fb2 + 768,  B2l + 96 + q8)   S2(2, a)
        PF(a, fb2 + 1024, B2l + 4 + q8)    S2(3, b)
        PF(b, fb2 + 1280, B2l + 36 + q8)   S2(4, a)
        PF(a, fb2 + 1536, B2l + 68 + q8)   S2(5, b)
        PF(b, fb2 + 1792, B2l + 100 + q8)  S2(6, a)
        S2(7, b)
    }

    // ---- final linear head
    float P0 = 0.f, P1 = 0.f;
    LNT8(HF)
    P0 += __shfl_xor(P0, 16); P0 += __shfl_xor(P0, 32);
    P1 += __shfl_xor(P1, 16); P1 += __shfl_xor(P1, 32);
    const float bf0 = bfp[0];
    if (q == 0) {
        int p0_ = base_pt + ln;
        if (p0_ < NP) out[p0_] = fmaf(P0, 0.5f, bf0);      // 0.5 = last-layer wgt2
        int p1_ = base_pt + 16 + ln;
        if (p1_ < NP) out[p1_] = fmaf(P1, 0.5f, bf0);
    }
}

extern "C" void kernel_launch(void* const* d_in, const int* in_sizes, int n_in,
                              void* d_out, int out_size, void* d_ws, size_t ws_size,
                              hipStream_t stream) {
    const float* x   = (const float*)d_in[0];
    const float* w0  = (const float*)d_in[1];
    const float* b0  = (const float*)d_in[2];
    const float* rw1 = (const float*)d_in[3];
    const float* rb1 = (const float*)d_in[4];
    const float* rw2 = (const float*)d_in[5];
    const float* rb2 = (const float*)d_in[6];
    const float* wf  = (const float*)d_in[7];
    const float* bf  = (const float*)d_in[8];
    float* out = (float*)d_out;

    unsigned short* wsHi = (unsigned short*)d_ws;          // needs 917504 B
    unsigned short* wsLo = wsHi + FRAG_ELEMS;

    const int n = in_sizes[0] / 3;                          // 200000
    prep_kernel<<<112, 256, 0, stream>>>(rw1, rw2, wsHi, wsLo);
    const int grid = (n + 127) / 128;
    siren_mfma<<<grid, BT, 0, stream>>>(x, w0, b0, rb1, rb2, wf, bf,
                                        (const u4v*)wsHi, (const u4v*)wsLo,
                                        out, n);
}

// Round 12
// 365.416 us; speedup vs baseline: 1.0772x; 1.0772x over previous
//
#include <hip/hip_runtime.h>

// Neurcomp / SIREN MLP inference — round 18: r16 (champion 305us) + omega-fold
// + v_fract, retested in the now-issue-bound regime.
// r17 post-mortem: in-register h-fragment build triggered regalloc collapse
// (LDS demoted, 205MB scratch, 365us). Reverted. Lesson: r16's LDS round-trip
// is the pressure-relief valve that keeps the ~216-value live set in the
// 128V+128A unified file (H parked in AGPRs across mm1).
// r16 state: 88% issue (MFMA 41.7 + VALU 46.3); VALU (141us) is the pole.
// r15's omega-fold measured -21us VALU busy but failed on r14 (latency-bound:
// saved ops sat in stall shadows). r16 is issue-bound -> regime prerequisite
// now met; retest. Deltas vs r16 (ONLY these):
//  (1) K=omega/2pi folded into prep weights + bias at prefetch -> no per-sin mul;
//  (2) fractf instead of floorf+sub -> 1 fewer op per sin.
// Layouts (learn_hip m89/m120, r6/r8-verified): A[m=lane&15][k=(lane>>4)*8+j],
// B[k=(lane>>4)*8+j][n=lane&15], D row=(lane>>4)*4+reg, col=lane&15.
// A = weights, B = activations; D: feature row, point col.

typedef unsigned int u32;
typedef short s8v __attribute__((ext_vector_type(8)));   // 8 bf16 (bits)
typedef float f4v __attribute__((ext_vector_type(4)));
typedef u32   u4v __attribute__((ext_vector_type(4)));

constexpr float OMEGA = 30.0f;
constexpr float KREV = 4.7746482946f;  // OMEGA / (2*pi)
constexpr int HID = 128, NRES = 7, BT = 256;
constexpr int WROW = 136;              // dwords per LDS row: 32 b128-blocks + pad
constexpr int WAVE_LDS = 32 * WROW;    // 4352 dwords per wave (32 rows)
constexpr int FRAG_ELEMS = 14 * 16384; // bf16 elems per hi/lo ws array

__device__ __forceinline__ float sin_om(float z) {      // first layer only
    float r = z * (OMEGA * 0.15915494309189535f);
    return __builtin_amdgcn_sinf(__builtin_amdgcn_fractf(r));
}
__device__ __forceinline__ float sinrev(float r) {      // input in revolutions
    return __builtin_amdgcn_sinf(__builtin_amdgcn_fractf(r));
}
__device__ __forceinline__ f4v mfma16(s8v a, s8v b, f4v c) {
    return __builtin_amdgcn_mfma_f32_16x16x32_bf16(a, b, c, 0, 0, 0);
}
__device__ __forceinline__ u32 fu(float f) { return __builtin_bit_cast(u32, f); }
__device__ __forceinline__ float andf(float f) {
    return __builtin_bit_cast(float, __builtin_bit_cast(u32, f) & 0xffff0000u);
}
__device__ __forceinline__ s8v bc(u4v v) { return __builtin_bit_cast(s8v, v); }

// 8 fp32 (frag elem order j=0..7) -> hi s8v + lo s8v (truncation split).
// v_perm sel 0x07060302: D = {a.hi16 (top), b.hi16 (low)}.
#define PK8(e0,e1,e2,e3,e4,e5,e6,e7, FH_, FL_) { \
    u4v h_, l_; \
    h_.x = __builtin_amdgcn_perm(fu(e1), fu(e0), 0x07060302u); \
    h_.y = __builtin_amdgcn_perm(fu(e3), fu(e2), 0x07060302u); \
    h_.z = __builtin_amdgcn_perm(fu(e5), fu(e4), 0x07060302u); \
    h_.w = __builtin_amdgcn_perm(fu(e7), fu(e6), 0x07060302u); \
    float L0_ = e0 - andf(e0), L1_ = e1 - andf(e1); \
    float L2_ = e2 - andf(e2), L3_ = e3 - andf(e3); \
    float L4_ = e4 - andf(e4), L5_ = e5 - andf(e5); \
    float L6_ = e6 - andf(e6), L7_ = e7 - andf(e7); \
    l_.x = __builtin_amdgcn_perm(fu(L1_), fu(L0_), 0x07060302u); \
    l_.y = __builtin_amdgcn_perm(fu(L3_), fu(L2_), 0x07060302u); \
    l_.z = __builtin_amdgcn_perm(fu(L5_), fu(L4_), 0x07060302u); \
    l_.w = __builtin_amdgcn_perm(fu(L7_), fu(L6_), 0x07060302u); \
    FH_ = __builtin_bit_cast(s8v, h_); FL_ = __builtin_bit_cast(s8v, l_); }

// h (D-layout regs, feature 16nt+4q+reg at point-row) -> LDS, b128 swizzled.
#define WH(mt,nt) { \
    f4v hv_; hv_.x = H_##mt##_##nt##_0; hv_.y = H_##mt##_##nt##_1; \
    hv_.z = H_##mt##_##nt##_2; hv_.w = H_##mt##_##nt##_3; \
    *(f4v*)&buf[(mt ? rowbase1 : rowbase0) + ((((nt)*4 + q) ^ lnk) << 2)] = hv_; }

// LDS -> B-fragments, split-on-read.
#define RS(mt,kc) { \
    const int rb_ = mt ? rowbase1 : rowbase0; \
    f4v u_ = *(const f4v*)&buf[rb_ + ((((kc)*8 + q*2    ) ^ lnk) << 2)]; \
    f4v v_ = *(const f4v*)&buf[rb_ + ((((kc)*8 + q*2 + 1) ^ lnk) << 2)]; \
    PK8(u_.x, u_.y, u_.z, u_.w, v_.x, v_.y, v_.z, v_.w, FH##mt##kc, FL##mt##kc) }

// prefetch weight tile + bias (scaled to revolutions) into buffer S (a or b)
#define PF(S, fbv, bp) { \
    g##S##0 = whi[fbv]; g##S##1 = whi[(fbv)+64]; \
    g##S##2 = whi[(fbv)+128]; g##S##3 = whi[(fbv)+192]; \
    r##S##0 = wlo[fbv]; r##S##1 = wlo[(fbv)+64]; \
    r##S##2 = wlo[(fbv)+128]; r##S##3 = wlo[(fbv)+192]; \
    cv##S = (*(const f4v*)(bp)) * KREV; }

// 24 MFMAs consuming buffer S — FOUR independent chains, round-robin (r16).
#define MMB4(S) { \
    s8v h0_=bc(g##S##0), l0_=bc(r##S##0), h1_=bc(g##S##1), l1_=bc(r##S##1); \
    s8v h2_=bc(g##S##2), l2_=bc(r##S##2), h3_=bc(g##S##3), l3_=bc(r##S##3); \
    c0  = mfma16(h0_, FH00, c0 ); c1  = mfma16(h0_, FH10, c1 ); \
    c0b = mfma16(h2_, FH02, c0b); c1b = mfma16(h2_, FH12, c1b); \
    c0  = mfma16(h0_, FL00, c0 ); c1  = mfma16(h0_, FL10, c1 ); \
    c0b = mfma16(h2_, FL02, c0b); c1b = mfma16(h2_, FL12, c1b); \
    c0  = mfma16(l0_, FH00, c0 ); c1  = mfma16(l0_, FH10, c1 ); \
    c0b = mfma16(l2_, FH02, c0b); c1b = mfma16(l2_, FH12, c1b); \
    c0  = mfma16(h1_, FH01, c0 ); c1  = mfma16(h1_, FH11, c1 ); \
    c0b = mfma16(h3_, FH03, c0b); c1b = mfma16(h3_, FH13, c1b); \
    c0  = mfma16(h1_, FL01, c0 ); c1  = mfma16(h1_, FL11, c1 ); \
    c0b = mfma16(h3_, FL03, c0b); c1b = mfma16(h3_, FL13, c1b); \
    c0  = mfma16(l1_, FH01, c0 ); c1  = mfma16(l1_, FH11, c1 ); \
    c0b = mfma16(l3_, FH03, c0b); c1b = mfma16(l3_, FH13, c1b); \
    c0 += c0b; c1 += c1b; }

// mm1 step t consuming buffer S: s1 = sin(acc_rev), staged to LDS
#define S1(t, S) { \
    f4v c0 = cv##S; f4v c1 = c0; \
    f4v c0b = {0.f, 0.f, 0.f, 0.f}; f4v c1b = c0b; \
    MMB4(S) \
    f4v s0v, s1v; \
    s0v.x = sinrev(c0.x); s0v.y = sinrev(c0.y); \
    s0v.z = sinrev(c0.z); s0v.w = sinrev(c0.w); \
    s1v.x = sinrev(c1.x); s1v.y = sinrev(c1.y); \
    s1v.z = sinrev(c1.z); s1v.w = sinrev(c1.w); \
    const int bo_ = (((t)*4 + q) ^ lnk) << 2; \
    *(f4v*)&buf[rowbase0 + bo_] = s0v; \
    *(f4v*)&buf[rowbase1 + bo_] = s1v; }

// mm2 step t consuming buffer S: epilogue h += s2 (last-layer 0.5 in head)
#define S2(t, S) { \
    f4v c0 = cv##S; f4v c1 = c0; \
    f4v c0b = {0.f, 0.f, 0.f, 0.f}; f4v c1b = c0b; \
    MMB4(S) \
    H_0_##t##_0 += sinrev(c0.x); H_0_##t##_1 += sinrev(c0.y); \
    H_0_##t##_2 += sinrev(c0.z); H_0_##t##_3 += sinrev(c0.w); \
    H_1_##t##_0 += sinrev(c1.x); H_1_##t##_1 += sinrev(c1.y); \
    H_1_##t##_2 += sinrev(c1.z); H_1_##t##_3 += sinrev(c1.w); }

// ---- repetition lists ----
#define LNT8(M) M(0) M(1) M(2) M(3) M(4) M(5) M(6) M(7)
#define LW16(M) M(0,0) M(0,1) M(0,2) M(0,3) M(0,4) M(0,5) M(0,6) M(0,7) \
                M(1,0) M(1,1) M(1,2) M(1,3) M(1,4) M(1,5) M(1,6) M(1,7)
#define LH64(M) \
  M(0,0,0) M(0,0,1) M(0,0,2) M(0,0,3) M(0,1,0) M(0,1,1) M(0,1,2) M(0,1,3) \
  M(0,2,0) M(0,2,1) M(0,2,2) M(0,2,3) M(0,3,0) M(0,3,1) M(0,3,2) M(0,3,3) \
  M(0,4,0) M(0,4,1) M(0,4,2) M(0,4,3) M(0,5,0) M(0,5,1) M(0,5,2) M(0,5,3) \
  M(0,6,0) M(0,6,1) M(0,6,2) M(0,6,3) M(0,7,0) M(0,7,1) M(0,7,2) M(0,7,3) \
  M(1,0,0) M(1,0,1) M(1,0,2) M(1,0,3) M(1,1,0) M(1,1,1) M(1,1,2) M(1,1,3) \
  M(1,2,0) M(1,2,1) M(1,2,2) M(1,2,3) M(1,3,0) M(1,3,1) M(1,3,2) M(1,3,3) \
  M(1,4,0) M(1,4,1) M(1,4,2) M(1,4,3) M(1,5,0) M(1,5,1) M(1,5,2) M(1,5,3) \
  M(1,6,0) M(1,6,1) M(1,6,2) M(1,6,3) M(1,7,0) M(1,7,1) M(1,7,2) M(1,7,3)

#define DH(mt,nt,reg) float H_##mt##_##nt##_##reg;

// first layer (unscaled w0 -> sin_om keeps the omega multiply)
#define F0(nt) { \
    f4v wa_ = *(const f4v*)(w0p + nt*48 + q*12); \
    f4v wb_ = *(const f4v*)(w0p + nt*48 + q*12 + 4); \
    f4v wc_ = *(const f4v*)(w0p + nt*48 + q*12 + 8); \
    f4v bb_ = *(const f4v*)(b0p + nt*16 + q4); \
    H_0_##nt##_0 = sin_om(fmaf(wa_.x, X0, fmaf(wa_.y, Y0, fmaf(wa_.z, Z0, bb_.x)))); \
    H_0_##nt##_1 = sin_om(fmaf(wa_.w, X0, fmaf(wb_.x, Y0, fmaf(wb_.y, Z0, bb_.y)))); \
    H_0_##nt##_2 = sin_om(fmaf(wb_.z, X0, fmaf(wb_.w, Y0, fmaf(wc_.x, Z0, bb_.z)))); \
    H_0_##nt##_3 = sin_om(fmaf(wc_.y, X0, fmaf(wc_.z, Y0, fmaf(wc_.w, Z0, bb_.w)))); \
    H_1_##nt##_0 = sin_om(fmaf(wa_.x, X1, fmaf(wa_.y, Y1, fmaf(wa_.z, Z1, bb_.x)))); \
    H_1_##nt##_1 = sin_om(fmaf(wa_.w, X1, fmaf(wb_.x, Y1, fmaf(wb_.y, Z1, bb_.y)))); \
    H_1_##nt##_2 = sin_om(fmaf(wb_.z, X1, fmaf(wb_.w, Y1, fmaf(wc_.x, Z1, bb_.z)))); \
    H_1_##nt##_3 = sin_om(fmaf(wc_.y, X1, fmaf(wc_.z, Y1, fmaf(wc_.w, Z1, bb_.w)))); }

// final head partials
#define HF(nt) { f4v wf_ = *(const f4v*)(wfp + nt*16 + q4); \
    P0 = fmaf(wf_.x, H_0_##nt##_0, fmaf(wf_.y, H_0_##nt##_1, \
         fmaf(wf_.z, H_0_##nt##_2, fmaf(wf_.w, H_0_##nt##_3, P0)))); \
    P1 = fmaf(wf_.x, H_1_##nt##_0, fmaf(wf_.y, H_1_##nt##_1, \
         fmaf(wf_.z, H_1_##nt##_2, fmaf(wf_.w, H_1_##nt##_3, P1)))); }

// ---- weight prep: fp32 W -> K-scaled hi/lo bf16 fragments (r16 layout) ----
__global__ void prep_kernel(const float* __restrict__ rw1,
                            const float* __restrict__ rw2,
                            unsigned short* __restrict__ wsHi,
                            unsigned short* __restrict__ wsLo) {
    int id = blockIdx.x * 256 + threadIdx.x;      // 0 .. 28671
    int lane = id & 63, kc = (id >> 6) & 3, t = (id >> 8) & 7, L = id >> 11;
    int i = L >> 1;
    bool isW1 = ((L & 1) == 0);
    const float* W = (isW1 ? rw1 : rw2) + i * HID * HID;
    // fold wgt1 (ave_first) AND omega/2pi (revolutions)
    float sc = ((isW1 && i > 0) ? 0.5f : 1.0f) * KREV;
    int n = t * 16 + (lane & 15);                  // output feature
    int k0 = kc * 32 + (lane >> 4) * 8;            // input feature base
    const float* src = W + n * HID + k0;           // W[n][k0..k0+7]
    int off = id * 8;
    for (int j = 0; j < 8; ++j) {
        float w = src[j] * sc;
        u32 b = __builtin_bit_cast(u32, w);
        u32 hb = b & 0xffff0000u;
        float lo = w - __builtin_bit_cast(float, hb);
        wsHi[off + j] = (unsigned short)(b >> 16);
        wsLo[off + j] = (unsigned short)(__builtin_bit_cast(u32, lo) >> 16);
    }
}

__global__ void __launch_bounds__(BT)
__attribute__((amdgpu_waves_per_eu(2, 2)))
siren_mfma(const float* __restrict__ x,
           const float* __restrict__ w0p, const float* __restrict__ b0p,
           const float* __restrict__ b1p, const float* __restrict__ b2p,
           const float* __restrict__ wfp, const float* __restrict__ bfp,
           const u4v* __restrict__ whi, const u4v* __restrict__ wlo,
           float* __restrict__ out, int NP)
{
    __shared__ float buf[4 * WAVE_LDS];            // 69632 B, wave-private staging

    const int tid = threadIdx.x;
    const int wv = tid >> 6, lane = tid & 63;
    const int ln = lane & 15, q = lane >> 4;
    const int q4 = q * 4;
    const int lnk = ln & 7;                        // LDS XOR-swizzle key (per row)
    const int rowbase0 = wv * WAVE_LDS + ln * WROW;        // mt0 row (point = ln)
    const int rowbase1 = rowbase0 + 16 * WROW;             // mt1 row (point = 16+ln)
    const int base_pt = blockIdx.x * 128 + wv * 32;

    // ---- first SineLayer, feature-major H
    LH64(DH)
    {
        int p0_ = base_pt + ln;      int i0_ = p0_ < NP ? p0_ : NP - 1;
        int p1_ = base_pt + 16 + ln; int i1_ = p1_ < NP ? p1_ : NP - 1;
        float X0 = x[3*i0_], Y0 = x[3*i0_+1], Z0 = x[3*i0_+2];
        float X1 = x[3*i1_], Y1 = x[3*i1_+1], Z1 = x[3*i1_+2];
        LNT8(F0)
    }

    // activation B-fragments (hi/lo) for 2 point-tiles x 4 k-chunks
    s8v FH00, FH01, FH02, FH03, FH10, FH11, FH12, FH13;
    s8v FL00, FL01, FL02, FL03, FL10, FL11, FL12, FL13;

    // ping-pong prefetch buffers
    u4v ga0, ga1, ga2, ga3, ra0, ra1, ra2, ra3;
    u4v gb0, gb1, gb2, gb3, rb0, rb1, rb2, rb3;
    f4v cva, cvb;

    for (int i = 0; i < NRES; ++i) {
        const int fb1 = (2*i) * 2048 + lane, fb2 = (2*i+1) * 2048 + lane;
        const float* __restrict__ B1l = b1p + i * HID;
        const float* __restrict__ B2l = b2p + i * HID;

        // prefetch mm1-t0 while the h transpose phase runs
        PF(a, fb1, B1l + q4)

        // h (D-layout) -> LDS -> B-fragments (swizzled b128 round-trip)
        LW16(WH)
        RS(0,0) RS(0,1) RS(0,2) RS(0,3)
        RS(1,0) RS(1,1) RS(1,2) RS(1,3)

        // ---- matmul1 -> s1, software-pipelined (prefetch t+1 before consume t)
        PF(b, fb1 + 256,  B1l + 16 + q4)   S1(0, a)
        PF(a, fb1 + 512,  B1l + 32 + q4)   S1(1, b)
        PF(b, fb1 + 768,  B1l + 48 + q4)   S1(2, a)
        PF(a, fb1 + 1024, B1l + 64 + q4)   S1(3, b)
        PF(b, fb1 + 1280, B1l + 80 + q4)   S1(4, a)
        PF(a, fb1 + 1536, B1l + 96 + q4)   S1(5, b)
        PF(b, fb1 + 1792, B1l + 112 + q4)  S1(6, a)
        PF(a, fb2,        B2l + q4)        S1(7, b)   // prefetch mm2-t0

        // s1 -> fragments (split-on-read)
        RS(0,0) RS(0,1) RS(0,2) RS(0,3)
        RS(1,0) RS(1,1) RS(1,2) RS(1,3)

        // ---- matmul2 -> s2; epilogue h += s2
        PF(b, fb2 + 256,  B2l + 16 + q4)   S2(0, a)
        PF(a, fb2 + 512,  B2l + 32 + q4)   S2(1, b)
        PF(b, fb2 + 768,  B2l + 48 + q4)   S2(2, a)
        PF(a, fb2 + 1024, B2l + 64 + q4)   S2(3, b)
        PF(b, fb2 + 1280, B2l + 80 + q4)   S2(4, a)
        PF(a, fb2 + 1536, B2l + 96 + q4)   S2(5, b)
        PF(b, fb2 + 1792, B2l + 112 + q4)  S2(6, a)
        S2(7, b)
    }

    // ---- final linear head
    float P0 = 0.f, P1 = 0.f;
    LNT8(HF)
    P0 += __shfl_xor(P0, 16); P0 += __shfl_xor(P0, 32);
    P1 += __shfl_xor(P1, 16); P1 += __shfl_xor(P1, 32);
    const float bf0 = bfp[0];
    if (q == 0) {
        int p0_ = base_pt + ln;
        if (p0_ < NP) out[p0_] = fmaf(P0, 0.5f, bf0);      // 0.5 = last-layer wgt2
        int p1_ = base_pt + 16 + ln;
        if (p1_ < NP) out[p1_] = fmaf(P1, 0.5f, bf0);
    }
}

extern "C" void kernel_launch(void* const* d_in, const int* in_sizes, int n_in,
                              void* d_out, int out_size, void* d_ws, size_t ws_size,
                              hipStream_t stream) {
    const float* x   = (const float*)d_in[0];
    const float* w0  = (const float*)d_in[1];
    const float* b0  = (const float*)d_in[2];
    const float* rw1 = (const float*)d_in[3];
    const float* rb1 = (const float*)d_in[4];
    const float* rw2 = (const float*)d_in[5];
    const float* rb2 = (const float*)d_in[6];
    const float* wf  = (const float*)d_in[7];
    const float* bf  = (const float*)d_in[8];
    float* out = (float*)d_out;

    unsigned short* wsHi = (unsigned short*)d_ws;          // needs 917504 B
    unsigned short* wsLo = wsHi + FRAG_ELEMS;

    const int n = in_sizes[0] / 3;                          // 200000
    prep_kernel<<<112, 256, 0, stream>>>(rw1, rw2, wsHi, wsLo);
    const int grid = (n + 127) / 128;
    siren_mfma<<<grid, BT, 0, stream>>>(x, w0, b0, rb1, rb2, wf, bf,
                                        (const u4v*)wsHi, (const u4v*)wsLo,
                                        out, n);
}

// Round 13
// 346.002 us; speedup vs baseline: 1.1377x; 1.0561x over previous
//
#include <hip/hip_runtime.h>

// Neurcomp / SIREN MLP inference — round 19: omega-fold done right (bias
// pre-scaled in prep; PF stays a pure load).
// r18 post-mortem: VALU busy dropped exactly as predicted (141->121us) but
// stall 12->25%. Root cause isolated: cv = load*KREV inside PF makes the bias
// load's waitcnt land at prefetch time (load->VALU dep), serializing each
// t-block's prefetch (~250cy x 112 blocks) — same poison in r15. The fold
// itself is good; the delivery was wrong.
// Fix: prep kernel writes KREV-scaled biases to a 7KB tail of d_ws; PF loads
// them raw (bit-identical dataflow to r16's PF). Zero runtime bias muls.
// Outputs bit-identical to r18 => absmax must read exactly 4.8828e-4.
// Everything else identical to r16/r18 (4-chain MMB4, ping-pong prefetch,
// LDS b128-swizzle round-trips, sinrev).
// Layouts (learn_hip m89/m120, r6/r8-verified): A[m=lane&15][k=(lane>>4)*8+j],
// B[k=(lane>>4)*8+j][n=lane&15], D row=(lane>>4)*4+reg, col=lane&15.
// A = weights, B = activations; D: feature row, point col.

typedef unsigned int u32;
typedef short s8v __attribute__((ext_vector_type(8)));   // 8 bf16 (bits)
typedef float f4v __attribute__((ext_vector_type(4)));
typedef u32   u4v __attribute__((ext_vector_type(4)));

constexpr float OMEGA = 30.0f;
constexpr float KREV = 4.7746482946f;  // OMEGA / (2*pi)
constexpr int HID = 128, NRES = 7, BT = 256;
constexpr int WROW = 136;              // dwords per LDS row: 32 b128-blocks + pad
constexpr int WAVE_LDS = 32 * WROW;    // 4352 dwords per wave (32 rows)
constexpr int FRAG_ELEMS = 14 * 16384; // bf16 elems per hi/lo ws array

__device__ __forceinline__ float sin_om(float z) {      // first layer only
    float r = z * (OMEGA * 0.15915494309189535f);
    return __builtin_amdgcn_sinf(__builtin_amdgcn_fractf(r));
}
__device__ __forceinline__ float sinrev(float r) {      // input in revolutions
    return __builtin_amdgcn_sinf(__builtin_amdgcn_fractf(r));
}
__device__ __forceinline__ f4v mfma16(s8v a, s8v b, f4v c) {
    return __builtin_amdgcn_mfma_f32_16x16x32_bf16(a, b, c, 0, 0, 0);
}
__device__ __forceinline__ u32 fu(float f) { return __builtin_bit_cast(u32, f); }
__device__ __forceinline__ float andf(float f) {
    return __builtin_bit_cast(float, __builtin_bit_cast(u32, f) & 0xffff0000u);
}
__device__ __forceinline__ s8v bc(u4v v) { return __builtin_bit_cast(s8v, v); }

// 8 fp32 (frag elem order j=0..7) -> hi s8v + lo s8v (truncation split).
// v_perm sel 0x07060302: D = {a.hi16 (top), b.hi16 (low)}.
#define PK8(e0,e1,e2,e3,e4,e5,e6,e7, FH_, FL_) { \
    u4v h_, l_; \
    h_.x = __builtin_amdgcn_perm(fu(e1), fu(e0), 0x07060302u); \
    h_.y = __builtin_amdgcn_perm(fu(e3), fu(e2), 0x07060302u); \
    h_.z = __builtin_amdgcn_perm(fu(e5), fu(e4), 0x07060302u); \
    h_.w = __builtin_amdgcn_perm(fu(e7), fu(e6), 0x07060302u); \
    float L0_ = e0 - andf(e0), L1_ = e1 - andf(e1); \
    float L2_ = e2 - andf(e2), L3_ = e3 - andf(e3); \
    float L4_ = e4 - andf(e4), L5_ = e5 - andf(e5); \
    float L6_ = e6 - andf(e6), L7_ = e7 - andf(e7); \
    l_.x = __builtin_amdgcn_perm(fu(L1_), fu(L0_), 0x07060302u); \
    l_.y = __builtin_amdgcn_perm(fu(L3_), fu(L2_), 0x07060302u); \
    l_.z = __builtin_amdgcn_perm(fu(L5_), fu(L4_), 0x07060302u); \
    l_.w = __builtin_amdgcn_perm(fu(L7_), fu(L6_), 0x07060302u); \
    FH_ = __builtin_bit_cast(s8v, h_); FL_ = __builtin_bit_cast(s8v, l_); }

// h (D-layout regs, feature 16nt+4q+reg at point-row) -> LDS, b128 swizzled.
#define WH(mt,nt) { \
    f4v hv_; hv_.x = H_##mt##_##nt##_0; hv_.y = H_##mt##_##nt##_1; \
    hv_.z = H_##mt##_##nt##_2; hv_.w = H_##mt##_##nt##_3; \
    *(f4v*)&buf[(mt ? rowbase1 : rowbase0) + ((((nt)*4 + q) ^ lnk) << 2)] = hv_; }

// LDS -> B-fragments, split-on-read.
#define RS(mt,kc) { \
    const int rb_ = mt ? rowbase1 : rowbase0; \
    f4v u_ = *(const f4v*)&buf[rb_ + ((((kc)*8 + q*2    ) ^ lnk) << 2)]; \
    f4v v_ = *(const f4v*)&buf[rb_ + ((((kc)*8 + q*2 + 1) ^ lnk) << 2)]; \
    PK8(u_.x, u_.y, u_.z, u_.w, v_.x, v_.y, v_.z, v_.w, FH##mt##kc, FL##mt##kc) }

// prefetch weight tile + pre-scaled bias into buffer S — PURE LOADS ONLY.
#define PF(S, fbv, bp) { \
    g##S##0 = whi[fbv]; g##S##1 = whi[(fbv)+64]; \
    g##S##2 = whi[(fbv)+128]; g##S##3 = whi[(fbv)+192]; \
    r##S##0 = wlo[fbv]; r##S##1 = wlo[(fbv)+64]; \
    r##S##2 = wlo[(fbv)+128]; r##S##3 = wlo[(fbv)+192]; \
    cv##S = *(const f4v*)(bp); }

// 24 MFMAs consuming buffer S — FOUR independent chains, round-robin (r16).
#define MMB4(S) { \
    s8v h0_=bc(g##S##0), l0_=bc(r##S##0), h1_=bc(g##S##1), l1_=bc(r##S##1); \
    s8v h2_=bc(g##S##2), l2_=bc(r##S##2), h3_=bc(g##S##3), l3_=bc(r##S##3); \
    c0  = mfma16(h0_, FH00, c0 ); c1  = mfma16(h0_, FH10, c1 ); \
    c0b = mfma16(h2_, FH02, c0b); c1b = mfma16(h2_, FH12, c1b); \
    c0  = mfma16(h0_, FL00, c0 ); c1  = mfma16(h0_, FL10, c1 ); \
    c0b = mfma16(h2_, FL02, c0b); c1b = mfma16(h2_, FL12, c1b); \
    c0  = mfma16(l0_, FH00, c0 ); c1  = mfma16(l0_, FH10, c1 ); \
    c0b = mfma16(l2_, FH02, c0b); c1b = mfma16(l2_, FH12, c1b); \
    c0  = mfma16(h1_, FH01, c0 ); c1  = mfma16(h1_, FH11, c1 ); \
    c0b = mfma16(h3_, FH03, c0b); c1b = mfma16(h3_, FH13, c1b); \
    c0  = mfma16(h1_, FL01, c0 ); c1  = mfma16(h1_, FL11, c1 ); \
    c0b = mfma16(h3_, FL03, c0b); c1b = mfma16(h3_, FL13, c1b); \
    c0  = mfma16(l1_, FH01, c0 ); c1  = mfma16(l1_, FH11, c1 ); \
    c0b = mfma16(l3_, FH03, c0b); c1b = mfma16(l3_, FH13, c1b); \
    c0 += c0b; c1 += c1b; }

// mm1 step t consuming buffer S: s1 = sin(acc_rev), staged to LDS
#define S1(t, S) { \
    f4v c0 = cv##S; f4v c1 = c0; \
    f4v c0b = {0.f, 0.f, 0.f, 0.f}; f4v c1b = c0b; \
    MMB4(S) \
    f4v s0v, s1v; \
    s0v.x = sinrev(c0.x); s0v.y = sinrev(c0.y); \
    s0v.z = sinrev(c0.z); s0v.w = sinrev(c0.w); \
    s1v.x = sinrev(c1.x); s1v.y = sinrev(c1.y); \
    s1v.z = sinrev(c1.z); s1v.w = sinrev(c1.w); \
    const int bo_ = (((t)*4 + q) ^ lnk) << 2; \
    *(f4v*)&buf[rowbase0 + bo_] = s0v; \
    *(f4v*)&buf[rowbase1 + bo_] = s1v; }

// mm2 step t consuming buffer S: epilogue h += s2 (last-layer 0.5 in head)
#define S2(t, S) { \
    f4v c0 = cv##S; f4v c1 = c0; \
    f4v c0b = {0.f, 0.f, 0.f, 0.f}; f4v c1b = c0b; \
    MMB4(S) \
    H_0_##t##_0 += sinrev(c0.x); H_0_##t##_1 += sinrev(c0.y); \
    H_0_##t##_2 += sinrev(c0.z); H_0_##t##_3 += sinrev(c0.w); \
    H_1_##t##_0 += sinrev(c1.x); H_1_##t##_1 += sinrev(c1.y); \
    H_1_##t##_2 += sinrev(c1.z); H_1_##t##_3 += sinrev(c1.w); }

// ---- repetition lists ----
#define LNT8(M) M(0) M(1) M(2) M(3) M(4) M(5) M(6) M(7)
#define LW16(M) M(0,0) M(0,1) M(0,2) M(0,3) M(0,4) M(0,5) M(0,6) M(0,7) \
                M(1,0) M(1,1) M(1,2) M(1,3) M(1,4) M(1,5) M(1,6) M(1,7)
#define LH64(M) \
  M(0,0,0) M(0,0,1) M(0,0,2) M(0,0,3) M(0,1,0) M(0,1,1) M(0,1,2) M(0,1,3) \
  M(0,2,0) M(0,2,1) M(0,2,2) M(0,2,3) M(0,3,0) M(0,3,1) M(0,3,2) M(0,3,3) \
  M(0,4,0) M(0,4,1) M(0,4,2) M(0,4,3) M(0,5,0) M(0,5,1) M(0,5,2) M(0,5,3) \
  M(0,6,0) M(0,6,1) M(0,6,2) M(0,6,3) M(0,7,0) M(0,7,1) M(0,7,2) M(0,7,3) \
  M(1,0,0) M(1,0,1) M(1,0,2) M(1,0,3) M(1,1,0) M(1,1,1) M(1,1,2) M(1,1,3) \
  M(1,2,0) M(1,2,1) M(1,2,2) M(1,2,3) M(1,3,0) M(1,3,1) M(1,3,2) M(1,3,3) \
  M(1,4,0) M(1,4,1) M(1,4,2) M(1,4,3) M(1,5,0) M(1,5,1) M(1,5,2) M(1,5,3) \
  M(1,6,0) M(1,6,1) M(1,6,2) M(1,6,3) M(1,7,0) M(1,7,1) M(1,7,2) M(1,7,3)

#define DH(mt,nt,reg) float H_##mt##_##nt##_##reg;

// first layer (unscaled w0 -> sin_om keeps the omega multiply)
#define F0(nt) { \
    f4v wa_ = *(const f4v*)(w0p + nt*48 + q*12); \
    f4v wb_ = *(const f4v*)(w0p + nt*48 + q*12 + 4); \
    f4v wc_ = *(const f4v*)(w0p + nt*48 + q*12 + 8); \
    f4v bb_ = *(const f4v*)(b0p + nt*16 + q4); \
    H_0_##nt##_0 = sin_om(fmaf(wa_.x, X0, fmaf(wa_.y, Y0, fmaf(wa_.z, Z0, bb_.x)))); \
    H_0_##nt##_1 = sin_om(fmaf(wa_.w, X0, fmaf(wb_.x, Y0, fmaf(wb_.y, Z0, bb_.y)))); \
    H_0_##nt##_2 = sin_om(fmaf(wb_.z, X0, fmaf(wb_.w, Y0, fmaf(wc_.x, Z0, bb_.z)))); \
    H_0_##nt##_3 = sin_om(fmaf(wc_.y, X0, fmaf(wc_.z, Y0, fmaf(wc_.w, Z0, bb_.w)))); \
    H_1_##nt##_0 = sin_om(fmaf(wa_.x, X1, fmaf(wa_.y, Y1, fmaf(wa_.z, Z1, bb_.x)))); \
    H_1_##nt##_1 = sin_om(fmaf(wa_.w, X1, fmaf(wb_.x, Y1, fmaf(wb_.y, Z1, bb_.y)))); \
    H_1_##nt##_2 = sin_om(fmaf(wb_.z, X1, fmaf(wb_.w, Y1, fmaf(wc_.x, Z1, bb_.z)))); \
    H_1_##nt##_3 = sin_om(fmaf(wc_.y, X1, fmaf(wc_.z, Y1, fmaf(wc_.w, Z1, bb_.w)))); }

// final head partials
#define HF(nt) { f4v wf_ = *(const f4v*)(wfp + nt*16 + q4); \
    P0 = fmaf(wf_.x, H_0_##nt##_0, fmaf(wf_.y, H_0_##nt##_1, \
         fmaf(wf_.z, H_0_##nt##_2, fmaf(wf_.w, H_0_##nt##_3, P0)))); \
    P1 = fmaf(wf_.x, H_1_##nt##_0, fmaf(wf_.y, H_1_##nt##_1, \
         fmaf(wf_.z, H_1_##nt##_2, fmaf(wf_.w, H_1_##nt##_3, P1)))); }

// ---- weight prep: fp32 W -> K-scaled hi/lo bf16 fragments (r16 layout);
// ALSO writes KREV-scaled biases to the d_ws tail (id < 1792).
__global__ void prep_kernel(const float* __restrict__ rw1,
                            const float* __restrict__ rw2,
                            const float* __restrict__ rb1,
                            const float* __restrict__ rb2,
                            unsigned short* __restrict__ wsHi,
                            unsigned short* __restrict__ wsLo,
                            float* __restrict__ wsBias) {
    int id = blockIdx.x * 256 + threadIdx.x;      // 0 .. 28671
    int lane = id & 63, kc = (id >> 6) & 3, t = (id >> 8) & 7, L = id >> 11;
    int i = L >> 1;
    bool isW1 = ((L & 1) == 0);
    const float* W = (isW1 ? rw1 : rw2) + i * HID * HID;
    // fold wgt1 (ave_first) AND omega/2pi (revolutions)
    float sc = ((isW1 && i > 0) ? 0.5f : 1.0f) * KREV;
    int n = t * 16 + (lane & 15);                  // output feature
    int k0 = kc * 32 + (lane >> 4) * 8;            // input feature base
    const float* src = W + n * HID + k0;           // W[n][k0..k0+7]
    int off = id * 8;
    for (int j = 0; j < 8; ++j) {
        float w = src[j] * sc;
        u32 b = __builtin_bit_cast(u32, w);
        u32 hb = b & 0xffff0000u;
        float lo = w - __builtin_bit_cast(float, hb);
        wsHi[off + j] = (unsigned short)(b >> 16);
        wsLo[off + j] = (unsigned short)(__builtin_bit_cast(u32, lo) >> 16);
    }
    if (id < 14 * HID) {                           // scaled biases: layer L', feat f
        int Lb = id >> 7, f = id & 127;
        int li = Lb >> 1;
        float bv = ((Lb & 1) == 0 ? rb1[li * HID + f] : rb2[li * HID + f]);
        wsBias[id] = bv * KREV;
    }
}

__global__ void __launch_bounds__(BT)
__attribute__((amdgpu_waves_per_eu(2, 2)))
siren_mfma(const float* __restrict__ x,
           const float* __restrict__ w0p, const float* __restrict__ b0p,
           const float* __restrict__ bwp,      // pre-scaled biases (d_ws tail)
           const float* __restrict__ wfp, const float* __restrict__ bfp,
           const u4v* __restrict__ whi, const u4v* __restrict__ wlo,
           float* __restrict__ out, int NP)
{
    __shared__ float buf[4 * WAVE_LDS];            // 69632 B, wave-private staging

    const int tid = threadIdx.x;
    const int wv = tid >> 6, lane = tid & 63;
    const int ln = lane & 15, q = lane >> 4;
    const int q4 = q * 4;
    const int lnk = ln & 7;                        // LDS XOR-swizzle key (per row)
    const int rowbase0 = wv * WAVE_LDS + ln * WROW;        // mt0 row (point = ln)
    const int rowbase1 = rowbase0 + 16 * WROW;             // mt1 row (point = 16+ln)
    const int base_pt = blockIdx.x * 128 + wv * 32;

    // ---- first SineLayer, feature-major H
    LH64(DH)
    {
        int p0_ = base_pt + ln;      int i0_ = p0_ < NP ? p0_ : NP - 1;
        int p1_ = base_pt + 16 + ln; int i1_ = p1_ < NP ? p1_ : NP - 1;
        float X0 = x[3*i0_], Y0 = x[3*i0_+1], Z0 = x[3*i0_+2];
        float X1 = x[3*i1_], Y1 = x[3*i1_+1], Z1 = x[3*i1_+2];
        LNT8(F0)
    }

    // activation B-fragments (hi/lo) for 2 point-tiles x 4 k-chunks
    s8v FH00, FH01, FH02, FH03, FH10, FH11, FH12, FH13;
    s8v FL00, FL01, FL02, FL03, FL10, FL11, FL12, FL13;

    // ping-pong prefetch buffers
    u4v ga0, ga1, ga2, ga3, ra0, ra1, ra2, ra3;
    u4v gb0, gb1, gb2, gb3, rb0, rb1, rb2, rb3;
    f4v cva, cvb;

    for (int i = 0; i < NRES; ++i) {
        const int fb1 = (2*i) * 2048 + lane, fb2 = (2*i+1) * 2048 + lane;
        const float* __restrict__ B1l = bwp + (2*i) * HID;
        const float* __restrict__ B2l = bwp + (2*i+1) * HID;

        // prefetch mm1-t0 while the h transpose phase runs
        PF(a, fb1, B1l + q4)

        // h (D-layout) -> LDS -> B-fragments (swizzled b128 round-trip)
        LW16(WH)
        RS(0,0) RS(0,1) RS(0,2) RS(0,3)
        RS(1,0) RS(1,1) RS(1,2) RS(1,3)

        // ---- matmul1 -> s1, software-pipelined (prefetch t+1 before consume t)
        PF(b, fb1 + 256,  B1l + 16 + q4)   S1(0, a)
        PF(a, fb1 + 512,  B1l + 32 + q4)   S1(1, b)
        PF(b, fb1 + 768,  B1l + 48 + q4)   S1(2, a)
        PF(a, fb1 + 1024, B1l + 64 + q4)   S1(3, b)
        PF(b, fb1 + 1280, B1l + 80 + q4)   S1(4, a)
        PF(a, fb1 + 1536, B1l + 96 + q4)   S1(5, b)
        PF(b, fb1 + 1792, B1l + 112 + q4)  S1(6, a)
        PF(a, fb2,        B2l + q4)        S1(7, b)   // prefetch mm2-t0

        // s1 -> fragments (split-on-read)
        RS(0,0) RS(0,1) RS(0,2) RS(0,3)
        RS(1,0) RS(1,1) RS(1,2) RS(1,3)

        // ---- matmul2 -> s2; epilogue h += s2
        PF(b, fb2 + 256,  B2l + 16 + q4)   S2(0, a)
        PF(a, fb2 + 512,  B2l + 32 + q4)   S2(1, b)
        PF(b, fb2 + 768,  B2l + 48 + q4)   S2(2, a)
        PF(a, fb2 + 1024, B2l + 64 + q4)   S2(3, b)
        PF(b, fb2 + 1280, B2l + 80 + q4)   S2(4, a)
        PF(a, fb2 + 1536, B2l + 96 + q4)   S2(5, b)
        PF(b, fb2 + 1792, B2l + 112 + q4)  S2(6, a)
        S2(7, b)
    }

    // ---- final linear head
    float P0 = 0.f, P1 = 0.f;
    LNT8(HF)
    P0 += __shfl_xor(P0, 16); P0 += __shfl_xor(P0, 32);
    P1 += __shfl_xor(P1, 16); P1 += __shfl_xor(P1, 32);
    const float bf0 = bfp[0];
    if (q == 0) {
        int p0_ = base_pt + ln;
        if (p0_ < NP) out[p0_] = fmaf(P0, 0.5f, bf0);      // 0.5 = last-layer wgt2
        int p1_ = base_pt + 16 + ln;
        if (p1_ < NP) out[p1_] = fmaf(P1, 0.5f, bf0);
    }
}

extern "C" void kernel_launch(void* const* d_in, const int* in_sizes, int n_in,
                              void* d_out, int out_size, void* d_ws, size_t ws_size,
                              hipStream_t stream) {
    const float* x   = (const float*)d_in[0];
    const float* w0  = (const float*)d_in[1];
    const float* b0  = (const float*)d_in[2];
    const float* rw1 = (const float*)d_in[3];
    const float* rb1 = (const float*)d_in[4];
    const float* rw2 = (const float*)d_in[5];
    const float* rb2 = (const float*)d_in[6];
    const float* wf  = (const float*)d_in[7];
    const float* bf  = (const float*)d_in[8];
    float* out = (float*)d_out;

    unsigned short* wsHi = (unsigned short*)d_ws;          // 458752 B
    unsigned short* wsLo = wsHi + FRAG_ELEMS;              // 458752 B
    float* wsBias = (float*)(wsLo + FRAG_ELEMS);           // 7168 B (total 924672)

    const int n = in_sizes[0] / 3;                          // 200000
    prep_kernel<<<112, 256, 0, stream>>>(rw1, rw2, rb1, rb2, wsHi, wsLo, wsBias);
    const int grid = (n + 127) / 128;
    siren_mfma<<<grid, BT, 0, stream>>>(x, w0, b0, wsBias, wf, bf,
                                        (const u4v*)wsHi, (const u4v*)wsLo,
                                        out, n);
}

// Round 14
// 344.608 us; speedup vs baseline: 1.1423x; 1.0040x over previous
//
#include <hip/hip_runtime.h>

// Neurcomp / SIREN MLP inference — round 20: r19 (champion 304.6us) + s_setprio
// around the MFMA clusters (catalog T5).
// r19 post-mortem: bias-prescale fixed r18's early-waitcnt poison (stall 25->19%,
// 332->304.6) but the -20us VALU busy bought ~0 wall: VALU is NOT the pole.
// Pipe model: MFMA 42% (128us) and VALU 39% (119us) on SEPARATE pipes (m114);
// issue-port use ~22%. The kernel is dependency-latency-bound at 2 waves/SIMD
// (LDS 69632B locks 2 blocks/CU; every LDS-shrink needs +32 regs -> 128/256
// budget catch-22, proven r9/r10/r12). Last mechanism-matched lever: T5 —
// waves here are UNSYNCED (no barriers), so the SIMD usually has one wave in
// MFMA and one in sin/pack/LDS; setprio(1) around the 24-MFMA cluster gives
// the MFMA wave issue preference (T5 pays on role-diverse waves, +4-7% attn;
// null only on lockstep). Zero numeric change vs r19.
// Layouts (learn_hip m89/m120, r6/r8-verified): A[m=lane&15][k=(lane>>4)*8+j],
// B[k=(lane>>4)*8+j][n=lane&15], D row=(lane>>4)*4+reg, col=lane&15.
// A = weights, B = activations; D: feature row, point col.

typedef unsigned int u32;
typedef short s8v __attribute__((ext_vector_type(8)));   // 8 bf16 (bits)
typedef float f4v __attribute__((ext_vector_type(4)));
typedef u32   u4v __attribute__((ext_vector_type(4)));

constexpr float OMEGA = 30.0f;
constexpr float KREV = 4.7746482946f;  // OMEGA / (2*pi)
constexpr int HID = 128, NRES = 7, BT = 256;
constexpr int WROW = 136;              // dwords per LDS row: 32 b128-blocks + pad
constexpr int WAVE_LDS = 32 * WROW;    // 4352 dwords per wave (32 rows)
constexpr int FRAG_ELEMS = 14 * 16384; // bf16 elems per hi/lo ws array

__device__ __forceinline__ float sin_om(float z) {      // first layer only
    float r = z * (OMEGA * 0.15915494309189535f);
    return __builtin_amdgcn_sinf(__builtin_amdgcn_fractf(r));
}
__device__ __forceinline__ float sinrev(float r) {      // input in revolutions
    return __builtin_amdgcn_sinf(__builtin_amdgcn_fractf(r));
}
__device__ __forceinline__ f4v mfma16(s8v a, s8v b, f4v c) {
    return __builtin_amdgcn_mfma_f32_16x16x32_bf16(a, b, c, 0, 0, 0);
}
__device__ __forceinline__ u32 fu(float f) { return __builtin_bit_cast(u32, f); }
__device__ __forceinline__ float andf(float f) {
    return __builtin_bit_cast(float, __builtin_bit_cast(u32, f) & 0xffff0000u);
}
__device__ __forceinline__ s8v bc(u4v v) { return __builtin_bit_cast(s8v, v); }

// 8 fp32 (frag elem order j=0..7) -> hi s8v + lo s8v (truncation split).
// v_perm sel 0x07060302: D = {a.hi16 (top), b.hi16 (low)}.
#define PK8(e0,e1,e2,e3,e4,e5,e6,e7, FH_, FL_) { \
    u4v h_, l_; \
    h_.x = __builtin_amdgcn_perm(fu(e1), fu(e0), 0x07060302u); \
    h_.y = __builtin_amdgcn_perm(fu(e3), fu(e2), 0x07060302u); \
    h_.z = __builtin_amdgcn_perm(fu(e5), fu(e4), 0x07060302u); \
    h_.w = __builtin_amdgcn_perm(fu(e7), fu(e6), 0x07060302u); \
    float L0_ = e0 - andf(e0), L1_ = e1 - andf(e1); \
    float L2_ = e2 - andf(e2), L3_ = e3 - andf(e3); \
    float L4_ = e4 - andf(e4), L5_ = e5 - andf(e5); \
    float L6_ = e6 - andf(e6), L7_ = e7 - andf(e7); \
    l_.x = __builtin_amdgcn_perm(fu(L1_), fu(L0_), 0x07060302u); \
    l_.y = __builtin_amdgcn_perm(fu(L3_), fu(L2_), 0x07060302u); \
    l_.z = __builtin_amdgcn_perm(fu(L5_), fu(L4_), 0x07060302u); \
    l_.w = __builtin_amdgcn_perm(fu(L7_), fu(L6_), 0x07060302u); \
    FH_ = __builtin_bit_cast(s8v, h_); FL_ = __builtin_bit_cast(s8v, l_); }

// h (D-layout regs, feature 16nt+4q+reg at point-row) -> LDS, b128 swizzled.
#define WH(mt,nt) { \
    f4v hv_; hv_.x = H_##mt##_##nt##_0; hv_.y = H_##mt##_##nt##_1; \
    hv_.z = H_##mt##_##nt##_2; hv_.w = H_##mt##_##nt##_3; \
    *(f4v*)&buf[(mt ? rowbase1 : rowbase0) + ((((nt)*4 + q) ^ lnk) << 2)] = hv_; }

// LDS -> B-fragments, split-on-read.
#define RS(mt,kc) { \
    const int rb_ = mt ? rowbase1 : rowbase0; \
    f4v u_ = *(const f4v*)&buf[rb_ + ((((kc)*8 + q*2    ) ^ lnk) << 2)]; \
    f4v v_ = *(const f4v*)&buf[rb_ + ((((kc)*8 + q*2 + 1) ^ lnk) << 2)]; \
    PK8(u_.x, u_.y, u_.z, u_.w, v_.x, v_.y, v_.z, v_.w, FH##mt##kc, FL##mt##kc) }

// prefetch weight tile + pre-scaled bias into buffer S — PURE LOADS ONLY.
#define PF(S, fbv, bp) { \
    g##S##0 = whi[fbv]; g##S##1 = whi[(fbv)+64]; \
    g##S##2 = whi[(fbv)+128]; g##S##3 = whi[(fbv)+192]; \
    r##S##0 = wlo[fbv]; r##S##1 = wlo[(fbv)+64]; \
    r##S##2 = wlo[(fbv)+128]; r##S##3 = wlo[(fbv)+192]; \
    cv##S = *(const f4v*)(bp); }

// 24 MFMAs consuming buffer S — FOUR independent chains, round-robin (r16),
// wrapped in s_setprio(1)/(0) (T5: favor the MFMA wave on the SIMD scheduler).
#define MMB4(S) { \
    s8v h0_=bc(g##S##0), l0_=bc(r##S##0), h1_=bc(g##S##1), l1_=bc(r##S##1); \
    s8v h2_=bc(g##S##2), l2_=bc(r##S##2), h3_=bc(g##S##3), l3_=bc(r##S##3); \
    __builtin_amdgcn_s_setprio(1); \
    c0  = mfma16(h0_, FH00, c0 ); c1  = mfma16(h0_, FH10, c1 ); \
    c0b = mfma16(h2_, FH02, c0b); c1b = mfma16(h2_, FH12, c1b); \
    c0  = mfma16(h0_, FL00, c0 ); c1  = mfma16(h0_, FL10, c1 ); \
    c0b = mfma16(h2_, FL02, c0b); c1b = mfma16(h2_, FL12, c1b); \
    c0  = mfma16(l0_, FH00, c0 ); c1  = mfma16(l0_, FH10, c1 ); \
    c0b = mfma16(l2_, FH02, c0b); c1b = mfma16(l2_, FH12, c1b); \
    c0  = mfma16(h1_, FH01, c0 ); c1  = mfma16(h1_, FH11, c1 ); \
    c0b = mfma16(h3_, FH03, c0b); c1b = mfma16(h3_, FH13, c1b); \
    c0  = mfma16(h1_, FL01, c0 ); c1  = mfma16(h1_, FL11, c1 ); \
    c0b = mfma16(h3_, FL03, c0b); c1b = mfma16(h3_, FL13, c1b); \
    c0  = mfma16(l1_, FH01, c0 ); c1  = mfma16(l1_, FH11, c1 ); \
    c0b = mfma16(l3_, FH03, c0b); c1b = mfma16(l3_, FH13, c1b); \
    __builtin_amdgcn_s_setprio(0); \
    c0 += c0b; c1 += c1b; }

// mm1 step t consuming buffer S: s1 = sin(acc_rev), staged to LDS
#define S1(t, S) { \
    f4v c0 = cv##S; f4v c1 = c0; \
    f4v c0b = {0.f, 0.f, 0.f, 0.f}; f4v c1b = c0b; \
    MMB4(S) \
    f4v s0v, s1v; \
    s0v.x = sinrev(c0.x); s0v.y = sinrev(c0.y); \
    s0v.z = sinrev(c0.z); s0v.w = sinrev(c0.w); \
    s1v.x = sinrev(c1.x); s1v.y = sinrev(c1.y); \
    s1v.z = sinrev(c1.z); s1v.w = sinrev(c1.w); \
    const int bo_ = (((t)*4 + q) ^ lnk) << 2; \
    *(f4v*)&buf[rowbase0 + bo_] = s0v; \
    *(f4v*)&buf[rowbase1 + bo_] = s1v; }

// mm2 step t consuming buffer S: epilogue h += s2 (last-layer 0.5 in head)
#define S2(t, S) { \
    f4v c0 = cv##S; f4v c1 = c0; \
    f4v c0b = {0.f, 0.f, 0.f, 0.f}; f4v c1b = c0b; \
    MMB4(S) \
    H_0_##t##_0 += sinrev(c0.x); H_0_##t##_1 += sinrev(c0.y); \
    H_0_##t##_2 += sinrev(c0.z); H_0_##t##_3 += sinrev(c0.w); \
    H_1_##t##_0 += sinrev(c1.x); H_1_##t##_1 += sinrev(c1.y); \
    H_1_##t##_2 += sinrev(c1.z); H_1_##t##_3 += sinrev(c1.w); }

// ---- repetition lists ----
#define LNT8(M) M(0) M(1) M(2) M(3) M(4) M(5) M(6) M(7)
#define LW16(M) M(0,0) M(0,1) M(0,2) M(0,3) M(0,4) M(0,5) M(0,6) M(0,7) \
                M(1,0) M(1,1) M(1,2) M(1,3) M(1,4) M(1,5) M(1,6) M(1,7)
#define LH64(M) \
  M(0,0,0) M(0,0,1) M(0,0,2) M(0,0,3) M(0,1,0) M(0,1,1) M(0,1,2) M(0,1,3) \
  M(0,2,0) M(0,2,1) M(0,2,2) M(0,2,3) M(0,3,0) M(0,3,1) M(0,3,2) M(0,3,3) \
  M(0,4,0) M(0,4,1) M(0,4,2) M(0,4,3) M(0,5,0) M(0,5,1) M(0,5,2) M(0,5,3) \
  M(0,6,0) M(0,6,1) M(0,6,2) M(0,6,3) M(0,7,0) M(0,7,1) M(0,7,2) M(0,7,3) \
  M(1,0,0) M(1,0,1) M(1,0,2) M(1,0,3) M(1,1,0) M(1,1,1) M(1,1,2) M(1,1,3) \
  M(1,2,0) M(1,2,1) M(1,2,2) M(1,2,3) M(1,3,0) M(1,3,1) M(1,3,2) M(1,3,3) \
  M(1,4,0) M(1,4,1) M(1,4,2) M(1,4,3) M(1,5,0) M(1,5,1) M(1,5,2) M(1,5,3) \
  M(1,6,0) M(1,6,1) M(1,6,2) M(1,6,3) M(1,7,0) M(1,7,1) M(1,7,2) M(1,7,3)

#define DH(mt,nt,reg) float H_##mt##_##nt##_##reg;

// first layer (unscaled w0 -> sin_om keeps the omega multiply)
#define F0(nt) { \
    f4v wa_ = *(const f4v*)(w0p + nt*48 + q*12); \
    f4v wb_ = *(const f4v*)(w0p + nt*48 + q*12 + 4); \
    f4v wc_ = *(const f4v*)(w0p + nt*48 + q*12 + 8); \
    f4v bb_ = *(const f4v*)(b0p + nt*16 + q4); \
    H_0_##nt##_0 = sin_om(fmaf(wa_.x, X0, fmaf(wa_.y, Y0, fmaf(wa_.z, Z0, bb_.x)))); \
    H_0_##nt##_1 = sin_om(fmaf(wa_.w, X0, fmaf(wb_.x, Y0, fmaf(wb_.y, Z0, bb_.y)))); \
    H_0_##nt##_2 = sin_om(fmaf(wb_.z, X0, fmaf(wb_.w, Y0, fmaf(wc_.x, Z0, bb_.z)))); \
    H_0_##nt##_3 = sin_om(fmaf(wc_.y, X0, fmaf(wc_.z, Y0, fmaf(wc_.w, Z0, bb_.w)))); \
    H_1_##nt##_0 = sin_om(fmaf(wa_.x, X1, fmaf(wa_.y, Y1, fmaf(wa_.z, Z1, bb_.x)))); \
    H_1_##nt##_1 = sin_om(fmaf(wa_.w, X1, fmaf(wb_.x, Y1, fmaf(wb_.y, Z1, bb_.y)))); \
    H_1_##nt##_2 = sin_om(fmaf(wb_.z, X1, fmaf(wb_.w, Y1, fmaf(wc_.x, Z1, bb_.z)))); \
    H_1_##nt##_3 = sin_om(fmaf(wc_.y, X1, fmaf(wc_.z, Y1, fmaf(wc_.w, Z1, bb_.w)))); }

// final head partials
#define HF(nt) { f4v wf_ = *(const f4v*)(wfp + nt*16 + q4); \
    P0 = fmaf(wf_.x, H_0_##nt##_0, fmaf(wf_.y, H_0_##nt##_1, \
         fmaf(wf_.z, H_0_##nt##_2, fmaf(wf_.w, H_0_##nt##_3, P0)))); \
    P1 = fmaf(wf_.x, H_1_##nt##_0, fmaf(wf_.y, H_1_##nt##_1, \
         fmaf(wf_.z, H_1_##nt##_2, fmaf(wf_.w, H_1_##nt##_3, P1)))); }

// ---- weight prep: fp32 W -> K-scaled hi/lo bf16 fragments (r16 layout);
// ALSO writes KREV-scaled biases to the d_ws tail (id < 1792).
__global__ void prep_kernel(const float* __restrict__ rw1,
                            const float* __restrict__ rw2,
                            const float* __restrict__ rb1,
                            const float* __restrict__ rb2,
                            unsigned short* __restrict__ wsHi,
                            unsigned short* __restrict__ wsLo,
                            float* __restrict__ wsBias) {
    int id = blockIdx.x * 256 + threadIdx.x;      // 0 .. 28671
    int lane = id & 63, kc = (id >> 6) & 3, t = (id >> 8) & 7, L = id >> 11;
    int i = L >> 1;
    bool isW1 = ((L & 1) == 0);
    const float* W = (isW1 ? rw1 : rw2) + i * HID * HID;
    // fold wgt1 (ave_first) AND omega/2pi (revolutions)
    float sc = ((isW1 && i > 0) ? 0.5f : 1.0f) * KREV;
    int n = t * 16 + (lane & 15);                  // output feature
    int k0 = kc * 32 + (lane >> 4) * 8;            // input feature base
    const float* src = W + n * HID + k0;           // W[n][k0..k0+7]
    int off = id * 8;
    for (int j = 0; j < 8; ++j) {
        float w = src[j] * sc;
        u32 b = __builtin_bit_cast(u32, w);
        u32 hb = b & 0xffff0000u;
        float lo = w - __builtin_bit_cast(float, hb);
        wsHi[off + j] = (unsigned short)(b >> 16);
        wsLo[off + j] = (unsigned short)(__builtin_bit_cast(u32, lo) >> 16);
    }
    if (id < 14 * HID) {                           // scaled biases: layer L', feat f
        int Lb = id >> 7, f = id & 127;
        int li = Lb >> 1;
        float bv = ((Lb & 1) == 0 ? rb1[li * HID + f] : rb2[li * HID + f]);
        wsBias[id] = bv * KREV;
    }
}

__global__ void __launch_bounds__(BT)
__attribute__((amdgpu_waves_per_eu(2, 2)))
siren_mfma(const float* __restrict__ x,
           const float* __restrict__ w0p, const float* __restrict__ b0p,
           const float* __restrict__ bwp,      // pre-scaled biases (d_ws tail)
           const float* __restrict__ wfp, const float* __restrict__ bfp,
           const u4v* __restrict__ whi, const u4v* __restrict__ wlo,
           float* __restrict__ out, int NP)
{
    __shared__ float buf[4 * WAVE_LDS];            // 69632 B, wave-private staging

    const int tid = threadIdx.x;
    const int wv = tid >> 6, lane = tid & 63;
    const int ln = lane & 15, q = lane >> 4;
    const int q4 = q * 4;
    const int lnk = ln & 7;                        // LDS XOR-swizzle key (per row)
    const int rowbase0 = wv * WAVE_LDS + ln * WROW;        // mt0 row (point = ln)
    const int rowbase1 = rowbase0 + 16 * WROW;             // mt1 row (point = 16+ln)
    const int base_pt = blockIdx.x * 128 + wv * 32;

    // ---- first SineLayer, feature-major H
    LH64(DH)
    {
        int p0_ = base_pt + ln;      int i0_ = p0_ < NP ? p0_ : NP - 1;
        int p1_ = base_pt + 16 + ln; int i1_ = p1_ < NP ? p1_ : NP - 1;
        float X0 = x[3*i0_], Y0 = x[3*i0_+1], Z0 = x[3*i0_+2];
        float X1 = x[3*i1_], Y1 = x[3*i1_+1], Z1 = x[3*i1_+2];
        LNT8(F0)
    }

    // activation B-fragments (hi/lo) for 2 point-tiles x 4 k-chunks
    s8v FH00, FH01, FH02, FH03, FH10, FH11, FH12, FH13;
    s8v FL00, FL01, FL02, FL03, FL10, FL11, FL12, FL13;

    // ping-pong prefetch buffers
    u4v ga0, ga1, ga2, ga3, ra0, ra1, ra2, ra3;
    u4v gb0, gb1, gb2, gb3, rb0, rb1, rb2, rb3;
    f4v cva, cvb;

    for (int i = 0; i < NRES; ++i) {
        const int fb1 = (2*i) * 2048 + lane, fb2 = (2*i+1) * 2048 + lane;
        const float* __restrict__ B1l = bwp + (2*i) * HID;
        const float* __restrict__ B2l = bwp + (2*i+1) * HID;

        // prefetch mm1-t0 while the h transpose phase runs
        PF(a, fb1, B1l + q4)

        // h (D-layout) -> LDS -> B-fragments (swizzled b128 round-trip)
        LW16(WH)
        RS(0,0) RS(0,1) RS(0,2) RS(0,3)
        RS(1,0) RS(1,1) RS(1,2) RS(1,3)

        // ---- matmul1 -> s1, software-pipelined (prefetch t+1 before consume t)
        PF(b, fb1 + 256,  B1l + 16 + q4)   S1(0, a)
        PF(a, fb1 + 512,  B1l + 32 + q4)   S1(1, b)
        PF(b, fb1 + 768,  B1l + 48 + q4)   S1(2, a)
        PF(a, fb1 + 1024, B1l + 64 + q4)   S1(3, b)
        PF(b, fb1 + 1280, B1l + 80 + q4)   S1(4, a)
        PF(a, fb1 + 1536, B1l + 96 + q4)   S1(5, b)
        PF(b, fb1 + 1792, B1l + 112 + q4)  S1(6, a)
        PF(a, fb2,        B2l + q4)        S1(7, b)   // prefetch mm2-t0

        // s1 -> fragments (split-on-read)
        RS(0,0) RS(0,1) RS(0,2) RS(0,3)
        RS(1,0) RS(1,1) RS(1,2) RS(1,3)

        // ---- matmul2 -> s2; epilogue h += s2
        PF(b, fb2 + 256,  B2l + 16 + q4)   S2(0, a)
        PF(a, fb2 + 512,  B2l + 32 + q4)   S2(1, b)
        PF(b, fb2 + 768,  B2l + 48 + q4)   S2(2, a)
        PF(a, fb2 + 1024, B2l + 64 + q4)   S2(3, b)
        PF(b, fb2 + 1280, B2l + 80 + q4)   S2(4, a)
        PF(a, fb2 + 1536, B2l + 96 + q4)   S2(5, b)
        PF(b, fb2 + 1792, B2l + 112 + q4)  S2(6, a)
        S2(7, b)
    }

    // ---- final linear head
    float P0 = 0.f, P1 = 0.f;
    LNT8(HF)
    P0 += __shfl_xor(P0, 16); P0 += __shfl_xor(P0, 32);
    P1 += __shfl_xor(P1, 16); P1 += __shfl_xor(P1, 32);
    const float bf0 = bfp[0];
    if (q == 0) {
        int p0_ = base_pt + ln;
        if (p0_ < NP) out[p0_] = fmaf(P0, 0.5f, bf0);      // 0.5 = last-layer wgt2
        int p1_ = base_pt + 16 + ln;
        if (p1_ < NP) out[p1_] = fmaf(P1, 0.5f, bf0);
    }
}

extern "C" void kernel_launch(void* const* d_in, const int* in_sizes, int n_in,
                              void* d_out, int out_size, void* d_ws, size_t ws_size,
                              hipStream_t stream) {
    const float* x   = (const float*)d_in[0];
    const float* w0  = (const float*)d_in[1];
    const float* b0  = (const float*)d_in[2];
    const float* rw1 = (const float*)d_in[3];
    const float* rb1 = (const float*)d_in[4];
    const float* rw2 = (const float*)d_in[5];
    const float* rb2 = (const float*)d_in[6];
    const float* wf  = (const float*)d_in[7];
    const float* bf  = (const float*)d_in[8];
    float* out = (float*)d_out;

    unsigned short* wsHi = (unsigned short*)d_ws;          // 458752 B
    unsigned short* wsLo = wsHi + FRAG_ELEMS;              // 458752 B
    float* wsBias = (float*)(wsLo + FRAG_ELEMS);           // 7168 B (total 924672)

    const int n = in_sizes[0] / 3;                          // 200000
    prep_kernel<<<112, 256, 0, stream>>>(rw1, rw2, rb1, rb2, wsHi, wsLo, wsBias);
    const int grid = (n + 127) / 128;
    siren_mfma<<<grid, BT, 0, stream>>>(x, w0, b0, wsBias, wf, bf,
                                        (const u4v*)wsHi, (const u4v*)wsLo,
                                        out, n);
}

// Round 15
// 342.224 us; speedup vs baseline: 1.1502x; 1.0070x over previous
//
#include <hip/hip_runtime.h>

// Neurcomp / SIREN MLP inference — round 21: r20 main kernel (unchanged) +
// parallelized/coalesced prep_kernel.
// r20 post-mortem: setprio kept (steady 304.6->300.4) but OFFICIAL dur_us
// (344.6) sits ~44us above the slowest main dispatch (304) — the harness
// times prep + main + overhead. prep was pathological: 112 blocks (112/256
// CUs idle), 8 serial scalar loads/thread at 512B inter-lane stride (64
// cacheline requests per wave-load, latency-bound on re-poisoned cold
// weights), 8 scalar u16 stores. Fix: 1 element/thread (896 blocks, all CUs),
// e=[L|t|kc|lane|j] -> 8 consecutive threads read 32B contiguous, writes
// fully coalesced consecutive u16. Per-element math identical (w=src*sc,
// truncation split) => outputs bit-identical, absmax must be 4.8828e-4.
// Main kernel: byte-identical to r20 (4-chain MMB4 + setprio, ping-pong PF,
// prescaled bias, LDS b128-swizzle round-trips).
// Layouts (learn_hip m89/m120, r6/r8-verified): A[m=lane&15][k=(lane>>4)*8+j],
// B[k=(lane>>4)*8+j][n=lane&15], D row=(lane>>4)*4+reg, col=lane&15.

typedef unsigned int u32;
typedef short s8v __attribute__((ext_vector_type(8)));   // 8 bf16 (bits)
typedef float f4v __attribute__((ext_vector_type(4)));
typedef u32   u4v __attribute__((ext_vector_type(4)));

constexpr float OMEGA = 30.0f;
constexpr float KREV = 4.7746482946f;  // OMEGA / (2*pi)
constexpr int HID = 128, NRES = 7, BT = 256;
constexpr int WROW = 136;              // dwords per LDS row: 32 b128-blocks + pad
constexpr int WAVE_LDS = 32 * WROW;    // 4352 dwords per wave (32 rows)
constexpr int FRAG_ELEMS = 14 * 16384; // bf16 elems per hi/lo ws array

__device__ __forceinline__ float sin_om(float z) {      // first layer only
    float r = z * (OMEGA * 0.15915494309189535f);
    return __builtin_amdgcn_sinf(__builtin_amdgcn_fractf(r));
}
__device__ __forceinline__ float sinrev(float r) {      // input in revolutions
    return __builtin_amdgcn_sinf(__builtin_amdgcn_fractf(r));
}
__device__ __forceinline__ f4v mfma16(s8v a, s8v b, f4v c) {
    return __builtin_amdgcn_mfma_f32_16x16x32_bf16(a, b, c, 0, 0, 0);
}
__device__ __forceinline__ u32 fu(float f) { return __builtin_bit_cast(u32, f); }
__device__ __forceinline__ float andf(float f) {
    return __builtin_bit_cast(float, __builtin_bit_cast(u32, f) & 0xffff0000u);
}
__device__ __forceinline__ s8v bc(u4v v) { return __builtin_bit_cast(s8v, v); }

// 8 fp32 (frag elem order j=0..7) -> hi s8v + lo s8v (truncation split).
// v_perm sel 0x07060302: D = {a.hi16 (top), b.hi16 (low)}.
#define PK8(e0,e1,e2,e3,e4,e5,e6,e7, FH_, FL_) { \
    u4v h_, l_; \
    h_.x = __builtin_amdgcn_perm(fu(e1), fu(e0), 0x07060302u); \
    h_.y = __builtin_amdgcn_perm(fu(e3), fu(e2), 0x07060302u); \
    h_.z = __builtin_amdgcn_perm(fu(e5), fu(e4), 0x07060302u); \
    h_.w = __builtin_amdgcn_perm(fu(e7), fu(e6), 0x07060302u); \
    float L0_ = e0 - andf(e0), L1_ = e1 - andf(e1); \
    float L2_ = e2 - andf(e2), L3_ = e3 - andf(e3); \
    float L4_ = e4 - andf(e4), L5_ = e5 - andf(e5); \
    float L6_ = e6 - andf(e6), L7_ = e7 - andf(e7); \
    l_.x = __builtin_amdgcn_perm(fu(L1_), fu(L0_), 0x07060302u); \
    l_.y = __builtin_amdgcn_perm(fu(L3_), fu(L2_), 0x07060302u); \
    l_.z = __builtin_amdgcn_perm(fu(L5_), fu(L4_), 0x07060302u); \
    l_.w = __builtin_amdgcn_perm(fu(L7_), fu(L6_), 0x07060302u); \
    FH_ = __builtin_bit_cast(s8v, h_); FL_ = __builtin_bit_cast(s8v, l_); }

// h (D-layout regs, feature 16nt+4q+reg at point-row) -> LDS, b128 swizzled.
#define WH(mt,nt) { \
    f4v hv_; hv_.x = H_##mt##_##nt##_0; hv_.y = H_##mt##_##nt##_1; \
    hv_.z = H_##mt##_##nt##_2; hv_.w = H_##mt##_##nt##_3; \
    *(f4v*)&buf[(mt ? rowbase1 : rowbase0) + ((((nt)*4 + q) ^ lnk) << 2)] = hv_; }

// LDS -> B-fragments, split-on-read.
#define RS(mt,kc) { \
    const int rb_ = mt ? rowbase1 : rowbase0; \
    f4v u_ = *(const f4v*)&buf[rb_ + ((((kc)*8 + q*2    ) ^ lnk) << 2)]; \
    f4v v_ = *(const f4v*)&buf[rb_ + ((((kc)*8 + q*2 + 1) ^ lnk) << 2)]; \
    PK8(u_.x, u_.y, u_.z, u_.w, v_.x, v_.y, v_.z, v_.w, FH##mt##kc, FL##mt##kc) }

// prefetch weight tile + pre-scaled bias into buffer S — PURE LOADS ONLY.
#define PF(S, fbv, bp) { \
    g##S##0 = whi[fbv]; g##S##1 = whi[(fbv)+64]; \
    g##S##2 = whi[(fbv)+128]; g##S##3 = whi[(fbv)+192]; \
    r##S##0 = wlo[fbv]; r##S##1 = wlo[(fbv)+64]; \
    r##S##2 = wlo[(fbv)+128]; r##S##3 = wlo[(fbv)+192]; \
    cv##S = *(const f4v*)(bp); }

// 24 MFMAs consuming buffer S — FOUR independent chains, round-robin (r16),
// wrapped in s_setprio(1)/(0) (T5, kept from r20).
#define MMB4(S) { \
    s8v h0_=bc(g##S##0), l0_=bc(r##S##0), h1_=bc(g##S##1), l1_=bc(r##S##1); \
    s8v h2_=bc(g##S##2), l2_=bc(r##S##2), h3_=bc(g##S##3), l3_=bc(r##S##3); \
    __builtin_amdgcn_s_setprio(1); \
    c0  = mfma16(h0_, FH00, c0 ); c1  = mfma16(h0_, FH10, c1 ); \
    c0b = mfma16(h2_, FH02, c0b); c1b = mfma16(h2_, FH12, c1b); \
    c0  = mfma16(h0_, FL00, c0 ); c1  = mfma16(h0_, FL10, c1 ); \
    c0b = mfma16(h2_, FL02, c0b); c1b = mfma16(h2_, FL12, c1b); \
    c0  = mfma16(l0_, FH00, c0 ); c1  = mfma16(l0_, FH10, c1 ); \
    c0b = mfma16(l2_, FH02, c0b); c1b = mfma16(l2_, FH12, c1b); \
    c0  = mfma16(h1_, FH01, c0 ); c1  = mfma16(h1_, FH11, c1 ); \
    c0b = mfma16(h3_, FH03, c0b); c1b = mfma16(h3_, FH13, c1b); \
    c0  = mfma16(h1_, FL01, c0 ); c1  = mfma16(h1_, FL11, c1 ); \
    c0b = mfma16(h3_, FL03, c0b); c1b = mfma16(h3_, FL13, c1b); \
    c0  = mfma16(l1_, FH01, c0 ); c1  = mfma16(l1_, FH11, c1 ); \
    c0b = mfma16(l3_, FH03, c0b); c1b = mfma16(l3_, FH13, c1b); \
    __builtin_amdgcn_s_setprio(0); \
    c0 += c0b; c1 += c1b; }

// mm1 step t consuming buffer S: s1 = sin(acc_rev), staged to LDS
#define S1(t, S) { \
    f4v c0 = cv##S; f4v c1 = c0; \
    f4v c0b = {0.f, 0.f, 0.f, 0.f}; f4v c1b = c0b; \
    MMB4(S) \
    f4v s0v, s1v; \
    s0v.x = sinrev(c0.x); s0v.y = sinrev(c0.y); \
    s0v.z = sinrev(c0.z); s0v.w = sinrev(c0.w); \
    s1v.x = sinrev(c1.x); s1v.y = sinrev(c1.y); \
    s1v.z = sinrev(c1.z); s1v.w = sinrev(c1.w); \
    const int bo_ = (((t)*4 + q) ^ lnk) << 2; \
    *(f4v*)&buf[rowbase0 + bo_] = s0v; \
    *(f4v*)&buf[rowbase1 + bo_] = s1v; }

// mm2 step t consuming buffer S: epilogue h += s2 (last-layer 0.5 in head)
#define S2(t, S) { \
    f4v c0 = cv##S; f4v c1 = c0; \
    f4v c0b = {0.f, 0.f, 0.f, 0.f}; f4v c1b = c0b; \
    MMB4(S) \
    H_0_##t##_0 += sinrev(c0.x); H_0_##t##_1 += sinrev(c0.y); \
    H_0_##t##_2 += sinrev(c0.z); H_0_##t##_3 += sinrev(c0.w); \
    H_1_##t##_0 += sinrev(c1.x); H_1_##t##_1 += sinrev(c1.y); \
    H_1_##t##_2 += sinrev(c1.z); H_1_##t##_3 += sinrev(c1.w); }

// ---- repetition lists ----
#define LNT8(M) M(0) M(1) M(2) M(3) M(4) M(5) M(6) M(7)
#define LW16(M) M(0,0) M(0,1) M(0,2) M(0,3) M(0,4) M(0,5) M(0,6) M(0,7) \
                M(1,0) M(1,1) M(1,2) M(1,3) M(1,4) M(1,5) M(1,6) M(1,7)
#define LH64(M) \
  M(0,0,0) M(0,0,1) M(0,0,2) M(0,0,3) M(0,1,0) M(0,1,1) M(0,1,2) M(0,1,3) \
  M(0,2,0) M(0,2,1) M(0,2,2) M(0,2,3) M(0,3,0) M(0,3,1) M(0,3,2) M(0,3,3) \
  M(0,4,0) M(0,4,1) M(0,4,2) M(0,4,3) M(0,5,0) M(0,5,1) M(0,5,2) M(0,5,3) \
  M(0,6,0) M(0,6,1) M(0,6,2) M(0,6,3) M(0,7,0) M(0,7,1) M(0,7,2) M(0,7,3) \
  M(1,0,0) M(1,0,1) M(1,0,2) M(1,0,3) M(1,1,0) M(1,1,1) M(1,1,2) M(1,1,3) \
  M(1,2,0) M(1,2,1) M(1,2,2) M(1,2,3) M(1,3,0) M(1,3,1) M(1,3,2) M(1,3,3) \
  M(1,4,0) M(1,4,1) M(1,4,2) M(1,4,3) M(1,5,0) M(1,5,1) M(1,5,2) M(1,5,3) \
  M(1,6,0) M(1,6,1) M(1,6,2) M(1,6,3) M(1,7,0) M(1,7,1) M(1,7,2) M(1,7,3)

#define DH(mt,nt,reg) float H_##mt##_##nt##_##reg;

// first layer (unscaled w0 -> sin_om keeps the omega multiply)
#define F0(nt) { \
    f4v wa_ = *(const f4v*)(w0p + nt*48 + q*12); \
    f4v wb_ = *(const f4v*)(w0p + nt*48 + q*12 + 4); \
    f4v wc_ = *(const f4v*)(w0p + nt*48 + q*12 + 8); \
    f4v bb_ = *(const f4v*)(b0p + nt*16 + q4); \
    H_0_##nt##_0 = sin_om(fmaf(wa_.x, X0, fmaf(wa_.y, Y0, fmaf(wa_.z, Z0, bb_.x)))); \
    H_0_##nt##_1 = sin_om(fmaf(wa_.w, X0, fmaf(wb_.x, Y0, fmaf(wb_.y, Z0, bb_.y)))); \
    H_0_##nt##_2 = sin_om(fmaf(wb_.z, X0, fmaf(wb_.w, Y0, fmaf(wc_.x, Z0, bb_.z)))); \
    H_0_##nt##_3 = sin_om(fmaf(wc_.y, X0, fmaf(wc_.z, Y0, fmaf(wc_.w, Z0, bb_.w)))); \
    H_1_##nt##_0 = sin_om(fmaf(wa_.x, X1, fmaf(wa_.y, Y1, fmaf(wa_.z, Z1, bb_.x)))); \
    H_1_##nt##_1 = sin_om(fmaf(wa_.w, X1, fmaf(wb_.x, Y1, fmaf(wb_.y, Z1, bb_.y)))); \
    H_1_##nt##_2 = sin_om(fmaf(wb_.z, X1, fmaf(wb_.w, Y1, fmaf(wc_.x, Z1, bb_.z)))); \
    H_1_##nt##_3 = sin_om(fmaf(wc_.y, X1, fmaf(wc_.z, Y1, fmaf(wc_.w, Z1, bb_.w)))); }

// final head partials
#define HF(nt) { f4v wf_ = *(const f4v*)(wfp + nt*16 + q4); \
    P0 = fmaf(wf_.x, H_0_##nt##_0, fmaf(wf_.y, H_0_##nt##_1, \
         fmaf(wf_.z, H_0_##nt##_2, fmaf(wf_.w, H_0_##nt##_3, P0)))); \
    P1 = fmaf(wf_.x, H_1_##nt##_0, fmaf(wf_.y, H_1_##nt##_1, \
         fmaf(wf_.z, H_1_##nt##_2, fmaf(wf_.w, H_1_##nt##_3, P1)))); }

// ---- weight prep (REWORKED): 1 element/thread, coalesced.
// elem e = [L:4][t:3][kc:2][lane:6][j:3]; frag elem offset == e (same layout
// as r20: off = id*8 + j with id = [L|t|kc|lane]). Per-element math identical:
// w = W[n*HID + k0 + j] * sc, truncation hi/lo split. 8 consecutive threads
// read 32B contiguous; wsHi/wsLo writes fully coalesced. First 1792 threads
// also write the KREV-scaled bias tail.
__global__ void prep_kernel(const float* __restrict__ rw1,
                            const float* __restrict__ rw2,
                            const float* __restrict__ rb1,
                            const float* __restrict__ rb2,
                            unsigned short* __restrict__ wsHi,
                            unsigned short* __restrict__ wsLo,
                            float* __restrict__ wsBias) {
    int e = blockIdx.x * 256 + threadIdx.x;       // 0 .. 229375
    int j = e & 7, lane = (e >> 3) & 63, kc = (e >> 9) & 3;
    int t = (e >> 11) & 7, L = e >> 14;
    int i = L >> 1;
    bool isW1 = ((L & 1) == 0);
    const float* W = (isW1 ? rw1 : rw2) + i * HID * HID;
    float sc = ((isW1 && i > 0) ? 0.5f : 1.0f) * KREV;   // wgt1 + omega/2pi fold
    int n = t * 16 + (lane & 15);                  // output feature
    int k0 = kc * 32 + (lane >> 4) * 8;            // input feature base
    float w = W[n * HID + k0 + j] * sc;
    u32 b = __builtin_bit_cast(u32, w);
    u32 hb = b & 0xffff0000u;
    float lo = w - __builtin_bit_cast(float, hb);
    wsHi[e] = (unsigned short)(b >> 16);
    wsLo[e] = (unsigned short)(__builtin_bit_cast(u32, lo) >> 16);
    if (e < 14 * HID) {                            // scaled biases: layer Lb, feat f
        int Lb = e >> 7, f = e & 127;
        int li = Lb >> 1;
        float bv = ((Lb & 1) == 0 ? rb1[li * HID + f] : rb2[li * HID + f]);
        wsBias[e] = bv * KREV;
    }
}

__global__ void __launch_bounds__(BT)
__attribute__((amdgpu_waves_per_eu(2, 2)))
siren_mfma(const float* __restrict__ x,
           const float* __restrict__ w0p, const float* __restrict__ b0p,
           const float* __restrict__ bwp,      // pre-scaled biases (d_ws tail)
           const float* __restrict__ wfp, const float* __restrict__ bfp,
           const u4v* __restrict__ whi, const u4v* __restrict__ wlo,
           float* __restrict__ out, int NP)
{
    __shared__ float buf[4 * WAVE_LDS];            // 69632 B, wave-private staging

    const int tid = threadIdx.x;
    const int wv = tid >> 6, lane = tid & 63;
    const int ln = lane & 15, q = lane >> 4;
    const int q4 = q * 4;
    const int lnk = ln & 7;                        // LDS XOR-swizzle key (per row)
    const int rowbase0 = wv * WAVE_LDS + ln * WROW;        // mt0 row (point = ln)
    const int rowbase1 = rowbase0 + 16 * WROW;             // mt1 row (point = 16+ln)
    const int base_pt = blockIdx.x * 128 + wv * 32;

    // ---- first SineLayer, feature-major H
    LH64(DH)
    {
        int p0_ = base_pt + ln;      int i0_ = p0_ < NP ? p0_ : NP - 1;
        int p1_ = base_pt + 16 + ln; int i1_ = p1_ < NP ? p1_ : NP - 1;
        float X0 = x[3*i0_], Y0 = x[3*i0_+1], Z0 = x[3*i0_+2];
        float X1 = x[3*i1_], Y1 = x[3*i1_+1], Z1 = x[3*i1_+2];
        LNT8(F0)
    }

    // activation B-fragments (hi/lo) for 2 point-tiles x 4 k-chunks
    s8v FH00, FH01, FH02, FH03, FH10, FH11, FH12, FH13;
    s8v FL00, FL01, FL02, FL03, FL10, FL11, FL12, FL13;

    // ping-pong prefetch buffers
    u4v ga0, ga1, ga2, ga3, ra0, ra1, ra2, ra3;
    u4v gb0, gb1, gb2, gb3, rb0, rb1, rb2, rb3;
    f4v cva, cvb;

    for (int i = 0; i < NRES; ++i) {
        const int fb1 = (2*i) * 2048 + lane, fb2 = (2*i+1) * 2048 + lane;
        const float* __restrict__ B1l = bwp + (2*i) * HID;
        const float* __restrict__ B2l = bwp + (2*i+1) * HID;

        // prefetch mm1-t0 while the h transpose phase runs
        PF(a, fb1, B1l + q4)

        // h (D-layout) -> LDS -> B-fragments (swizzled b128 round-trip)
        LW16(WH)
        RS(0,0) RS(0,1) RS(0,2) RS(0,3)
        RS(1,0) RS(1,1) RS(1,2) RS(1,3)

        // ---- matmul1 -> s1, software-pipelined (prefetch t+1 before consume t)
        PF(b, fb1 + 256,  B1l + 16 + q4)   S1(0, a)
        PF(a, fb1 + 512,  B1l + 32 + q4)   S1(1, b)
        PF(b, fb1 + 768,  B1l + 48 + q4)   S1(2, a)
        PF(a, fb1 + 1024, B1l + 64 + q4)   S1(3, b)
        PF(b, fb1 + 1280, B1l + 80 + q4)   S1(4, a)
        PF(a, fb1 + 1536, B1l + 96 + q4)   S1(5, b)
        PF(b, fb1 + 1792, B1l + 112 + q4)  S1(6, a)
        PF(a, fb2,        B2l + q4)        S1(7, b)   // prefetch mm2-t0

        // s1 -> fragments (split-on-read)
        RS(0,0) RS(0,1) RS(0,2) RS(0,3)
        RS(1,0) RS(1,1) RS(1,2) RS(1,3)

        // ---- matmul2 -> s2; epilogue h += s2
        PF(b, fb2 + 256,  B2l + 16 + q4)   S2(0, a)
        PF(a, fb2 + 512,  B2l + 32 + q4)   S2(1, b)
        PF(b, fb2 + 768,  B2l + 48 + q4)   S2(2, a)
        PF(a, fb2 + 1024, B2l + 64 + q4)   S2(3, b)
        PF(b, fb2 + 1280, B2l + 80 + q4)   S2(4, a)
        PF(a, fb2 + 1536, B2l + 96 + q4)   S2(5, b)
        PF(b, fb2 + 1792, B2l + 112 + q4)  S2(6, a)
        S2(7, b)
    }

    // ---- final linear head
    float P0 = 0.f, P1 = 0.f;
    LNT8(HF)
    P0 += __shfl_xor(P0, 16); P0 += __shfl_xor(P0, 32);
    P1 += __shfl_xor(P1, 16); P1 += __shfl_xor(P1, 32);
    const float bf0 = bfp[0];
    if (q == 0) {
        int p0_ = base_pt + ln;
        if (p0_ < NP) out[p0_] = fmaf(P0, 0.5f, bf0);      // 0.5 = last-layer wgt2
        int p1_ = base_pt + 16 + ln;
        if (p1_ < NP) out[p1_] = fmaf(P1, 0.5f, bf0);
    }
}

extern "C" void kernel_launch(void* const* d_in, const int* in_sizes, int n_in,
                              void* d_out, int out_size, void* d_ws, size_t ws_size,
                              hipStream_t stream) {
    const float* x   = (const float*)d_in[0];
    const float* w0  = (const float*)d_in[1];
    const float* b0  = (const float*)d_in[2];
    const float* rw1 = (const float*)d_in[3];
    const float* rb1 = (const float*)d_in[4];
    const float* rw2 = (const float*)d_in[5];
    const float* rb2 = (const float*)d_in[6];
    const float* wf  = (const float*)d_in[7];
    const float* bf  = (const float*)d_in[8];
    float* out = (float*)d_out;

    unsigned short* wsHi = (unsigned short*)d_ws;          // 458752 B
    unsigned short* wsLo = wsHi + FRAG_ELEMS;              // 458752 B
    float* wsBias = (float*)(wsLo + FRAG_ELEMS);           // 7168 B (total 924672)

    const int n = in_sizes[0] / 3;                          // 200000
    prep_kernel<<<896, 256, 0, stream>>>(rw1, rw2, rb1, rb2, wsHi, wsLo, wsBias);
    const int grid = (n + 127) / 128;
    siren_mfma<<<grid, BT, 0, stream>>>(x, w0, b0, wsBias, wf, bf,
                                        (const u4v*)wsHi, (const u4v*)wsLo,
                                        out, n);
}